// Round 7
// baseline (509.801 us; speedup 1.0000x reference)
//
#include <hip/hip_runtime.h>
#include <math.h>

#define B_ 8
#define S_ 1024
#define E_ 1024
#define H_ 16
#define FF_ 4096

typedef __attribute__((ext_vector_type(8))) short bf16x8;
typedef __attribute__((ext_vector_type(4))) float f32x4;

#define QSCALE 0.1803368801111f  // 0.125 * log2(e)
#define LG2_10K 0.4152410118f    // log2(10000)/32

__device__ __forceinline__ unsigned short f2bf(float f) {
  union { float f; unsigned u; } v;
  v.f = f;
  unsigned r = v.u + 0x7fffu + ((v.u >> 16) & 1u);
  return (unsigned short)(r >> 16);
}
__device__ __forceinline__ float bf2f(unsigned short u) {
  union { unsigned u; float f; } v;
  v.u = ((unsigned)u) << 16;
  return v.f;
}
__device__ __forceinline__ unsigned fbits(float f) {
  union { float f; unsigned u; } v;
  v.f = f;
  return v.u;
}

__device__ __forceinline__ void glds16(const void* g, void* l) {
  __builtin_amdgcn_global_load_lds(
      (const __attribute__((address_space(1))) unsigned int*)g,
      (__attribute__((address_space(3))) unsigned int*)l, 16, 0, 0);
}

// ---------------- prep: all weight converts (fp32 [K][N] -> bf16 [N][K]) + bias pack ----
__global__ __launch_bounds__(256) void prep(const float* __restrict__ WQ,
                                            const float* __restrict__ WK,
                                            const float* __restrict__ WV,
                                            const float* __restrict__ WO,
                                            const float* __restrict__ W1,
                                            const float* __restrict__ W2,
                                            const float* __restrict__ bQ,
                                            const float* __restrict__ bK,
                                            const float* __restrict__ bV,
                                            unsigned short* __restrict__ WQKVt,
                                            unsigned short* __restrict__ WOt,
                                            unsigned short* __restrict__ W1t,
                                            unsigned short* __restrict__ W2t,
                                            float* __restrict__ bqkv) {
  const int id = blockIdx.x;
  if (id >= 12288) {
    const int i = (id - 12288) * 256 + threadIdx.x;
    if (i < 3072)
      bqkv[i] = (i < 1024) ? bQ[i] : ((i < 2048) ? bK[i - 1024] : bV[i - 2048]);
    return;
  }
  const float* W;
  unsigned short* D;
  int K, N, x, y;
  if (id < 4096) {
    const int m = id >> 10;
    const float* ws4[4] = {WQ, WK, WV, WO};
    unsigned short* ds4[4] = {WQKVt, WQKVt + 1024 * 1024, WQKVt + 2 * 1024 * 1024, WOt};
    W = ws4[m]; D = ds4[m]; K = 1024; N = 1024;
    x = id & 31; y = (id >> 5) & 31;
  } else if (id < 8192) {
    const int j = id - 4096;
    W = W1; D = W1t; K = 1024; N = 4096;
    x = j & 127; y = j >> 7;
  } else {
    const int j = id - 8192;
    W = W2; D = W2t; K = 4096; N = 1024;
    x = j & 31; y = j >> 5;
  }
  __shared__ float t[32][33];
  const int tx = threadIdx.x & 31, ty = threadIdx.x >> 5;
  const int n0 = x * 32, k0 = y * 32;
#pragma unroll
  for (int p = 0; p < 4; ++p)
    t[ty + p * 8][tx] = W[(size_t)(k0 + ty + p * 8) * N + n0 + tx];
  __syncthreads();
#pragma unroll
  for (int p = 0; p < 4; ++p)
    D[(size_t)(n0 + ty + p * 8) * K + k0 + tx] = f2bf(t[tx][ty + p * 8]);
}

// ---------------- RMSNorm: fp32 in, bf16 out; one block per row ----------------
__global__ __launch_bounds__(256) void rmsnorm_kernel(const float* __restrict__ x,
                                                      const float* __restrict__ g,
                                                      unsigned short* __restrict__ out) {
  const int row = blockIdx.x;
  const int t = threadIdx.x;
  const float4 v = ((const float4*)(x + (size_t)row * E_))[t];
  float ss = v.x * v.x + v.y * v.y + v.z * v.z + v.w * v.w;
#pragma unroll
  for (int off = 32; off > 0; off >>= 1) ss += __shfl_down(ss, off);
  __shared__ float sred[4];
  if ((t & 63) == 0) sred[t >> 6] = ss;
  __syncthreads();
  const float tot = sred[0] + sred[1] + sred[2] + sred[3];
  const float rinv = rsqrtf(tot * (1.0f / E_) + 1.1920929e-07f);
  const float4 gv = ((const float4*)g)[t];
  ushort4 o;
  o.x = f2bf(v.x * rinv * gv.x);
  o.y = f2bf(v.y * rinv * gv.y);
  o.z = f2bf(v.z * rinv * gv.z);
  o.w = f2bf(v.w * rinv * gv.w);
  ((ushort4*)(out + (size_t)row * E_))[t] = o;
}

// ======== 256x256 BK=64 8-phase pipelined GEMM, launch_bounds(512,1) ========
// Schedule verified R4/R5 (refcheck) and R6 (perf, FF2 < 81us under (512,1)).
// LDS unit = 1024 B = 8 rows x 128 B; phys slot s of row r holds logical k-slot
// s^r (source pre-swizzled, LDS dest linear, reads apply ^sw).
// Per phase: {ds_read frags | stage issue} -> barrier -> lgkmcnt(0) ->
// setprio(1) 16 MFMA setprio(0) -> [vmcnt(0) at p3/p7] -> barrier.
// t1 (->buf1, issued p0/p1) retired at p3 end; t2 (->buf0, p4/p5) at p7 end.
// (512,1): VGPR cap 512 -- the (512,2) cap of 256 spilled acc (+20..29MB
// scratch WRITE_SIZE, R4/R5). LDS 128KiB caps occupancy at 1 block/CU anyway.
template <int EPI, int SPLIT>
__global__ __launch_bounds__(512, 1) void gemm8p(const unsigned short* __restrict__ A,
                                                 const unsigned short* __restrict__ Bt,
                                                 const float* __restrict__ bias,
                                                 unsigned short* __restrict__ C,
                                                 int M, int N, int K) {
  __shared__ unsigned short Ls[2][2][256 * 64];
  const int tid = threadIdx.x;
  const int w = tid >> 6;
  const int lane = tid & 63;

  int id = blockIdx.x;
  int kh = 0;
  int nb = gridDim.x;
  if (SPLIT) { kh = id >> 7; id &= 127; nb = 128; }
  const int lid = (id & 7) * (nb >> 3) + (id >> 3);
  const int nbn = N >> 8;
  const int bm = (lid / nbn) * 256;
  const int bn = (lid % nbn) * 256;

  const int Kloc = SPLIT ? (K >> 1) : K;
  const unsigned short* Ab = A + (size_t)kh * Kloc;
  const unsigned short* Bb = Bt + (size_t)kh * Kloc;

  const int wm = (w & 1) * 128, wn = (w >> 1) * 64;

  f32x4 acc[8][4];
#pragma unroll
  for (int i = 0; i < 8; ++i)
#pragma unroll
    for (int j = 0; j < 4; ++j) acc[i][j] = (f32x4){0.f, 0.f, 0.f, 0.f};

  const int srow = lane >> 3;
  const int skb = (lane & 7) ^ srow;
  const unsigned short* Ap[4];
  const unsigned short* Bp[4];
#pragma unroll
  for (int p = 0; p < 4; ++p) {
    const int u = w * 4 + p;
    Ap[p] = Ab + (size_t)(bm + u * 8 + srow) * K + skb * 8;
    Bp[p] = Bb + (size_t)(bn + u * 8 + srow) * K + skb * 8;
  }

  const int fr = lane & 15;
  const int g = lane >> 4;
  const int sw = fr & 7;

  bf16x8 av[4], bv[4];

#define STG2(tt, sb, p0, p1)                                                  \
  {                                                                           \
    glds16(Ap[p0] + (size_t)(tt) * 64, &Ls[sb][0][(w * 4 + p0) * 512 + lane * 8]); \
    glds16(Bp[p0] + (size_t)(tt) * 64, &Ls[sb][1][(w * 4 + p0) * 512 + lane * 8]); \
    glds16(Ap[p1] + (size_t)(tt) * 64, &Ls[sb][0][(w * 4 + p1) * 512 + lane * 8]); \
    glds16(Bp[p1] + (size_t)(tt) * 64, &Ls[sb][1][(w * 4 + p1) * 512 + lane * 8]); \
  }
#define RDA(cb, kc, h)                                                        \
  _Pragma("unroll") for (int i4 = 0; i4 < 4; ++i4)                            \
      av[i4] = *(const bf16x8*)&Ls[cb][0][(wm + ((h) * 4 + i4) * 16 + fr) * 64 + \
                                          (((kc) * 4 + g) ^ sw) * 8];
#define RDB(cb, kc)                                                           \
  _Pragma("unroll") for (int in = 0; in < 4; ++in)                            \
      bv[in] = *(const bf16x8*)&Ls[cb][1][(wn + in * 16 + fr) * 64 +          \
                                          (((kc) * 4 + g) ^ sw) * 8];
#define LWAIT asm volatile("s_waitcnt lgkmcnt(0)" ::: "memory");
#define VDRAIN asm volatile("s_waitcnt vmcnt(0)" ::: "memory");
#define MFMA16(h)                                                             \
  __builtin_amdgcn_s_setprio(1);                                              \
  _Pragma("unroll") for (int i4 = 0; i4 < 4; ++i4)                            \
  _Pragma("unroll") for (int in = 0; in < 4; ++in)                            \
      acc[(h) * 4 + i4][in] = __builtin_amdgcn_mfma_f32_16x16x32_bf16(        \
          av[i4], bv[in], acc[(h) * 4 + i4][in], 0, 0, 0);                    \
  __builtin_amdgcn_s_setprio(0);

  const int nt = Kloc >> 6;
  const int ni = nt >> 1;

  STG2(0, 0, 0, 1);
  STG2(0, 0, 2, 3);
  VDRAIN;
  __builtin_amdgcn_s_barrier();

  for (int i = 0; i < ni; ++i) {
    const int t1 = 2 * i + 1;
    const int t2 = 2 * i + 2;

    RDB(0, 0); RDA(0, 0, 0);
    STG2(t1, 1, 0, 1);
    __builtin_amdgcn_s_barrier();
    LWAIT; MFMA16(0);
    __builtin_amdgcn_s_barrier();

    RDA(0, 0, 1);
    STG2(t1, 1, 2, 3);
    __builtin_amdgcn_s_barrier();
    LWAIT; MFMA16(1);
    __builtin_amdgcn_s_barrier();

    RDB(0, 1); RDA(0, 1, 0);
    __builtin_amdgcn_s_barrier();
    LWAIT; MFMA16(0);
    __builtin_amdgcn_s_barrier();

    RDA(0, 1, 1);
    __builtin_amdgcn_s_barrier();
    LWAIT; MFMA16(1);
    VDRAIN;
    __builtin_amdgcn_s_barrier();

    RDB(1, 0); RDA(1, 0, 0);
    if (t2 < nt) STG2(t2, 0, 0, 1);
    __builtin_amdgcn_s_barrier();
    LWAIT; MFMA16(0);
    __builtin_amdgcn_s_barrier();

    RDA(1, 0, 1);
    if (t2 < nt) STG2(t2, 0, 2, 3);
    __builtin_amdgcn_s_barrier();
    LWAIT; MFMA16(1);
    __builtin_amdgcn_s_barrier();

    RDB(1, 1); RDA(1, 1, 0);
    __builtin_amdgcn_s_barrier();
    LWAIT; MFMA16(0);
    __builtin_amdgcn_s_barrier();

    RDA(1, 1, 1);
    __builtin_amdgcn_s_barrier();
    LWAIT; MFMA16(1);
    VDRAIN;
    __builtin_amdgcn_s_barrier();
  }

  if (EPI == 0) {
#pragma unroll
    for (int im = 0; im < 8; ++im) {
      const int row0 = bm + wm + im * 16 + g * 4;
#pragma unroll
      for (int in = 0; in < 4; ++in) {
        const int col = bn + wn + in * 16 + fr;
        const float bvv = bias[col];
#pragma unroll
        for (int r = 0; r < 4; ++r) {
          float v = acc[im][in][r] + bvv;
          v = fmaxf(v, 0.0f);
          C[(size_t)(row0 + r) * N + col] = f2bf(v);
        }
      }
    }
  } else {
    unsigned short* P = C + (size_t)kh * ((size_t)M * N);
#pragma unroll
    for (int im = 0; im < 8; ++im) {
      const int row0 = bm + wm + im * 16 + g * 4;
#pragma unroll
      for (int in = 0; in < 4; ++in) {
        const int col = bn + wn + in * 16 + fr;
#pragma unroll
        for (int r = 0; r < 4; ++r)
          P[(size_t)(row0 + r) * N + col] = f2bf(acc[im][in][r]);
      }
    }
  }
#undef STG2
#undef RDA
#undef RDB
#undef LWAIT
#undef VDRAIN
#undef MFMA16
}

// ---------------- FF2 combine: out = x1 + b2 + P0 + P1 ----------------
__global__ __launch_bounds__(256) void ff2_reduce(const unsigned short* __restrict__ Pp,
                                                  const float* __restrict__ x1,
                                                  const float* __restrict__ b2,
                                                  float* __restrict__ out) {
  const int i = blockIdx.x * 256 + threadIdx.x;
  const size_t off = (size_t)i * 4;
  const ushort4 p0 = *(const ushort4*)(Pp + off);
  const ushort4 p1 = *(const ushort4*)(Pp + (8u << 20) + off);
  const float4 xv = *(const float4*)(x1 + off);
  const float4 bv = *(const float4*)(b2 + (off & 1023));
  float4 o;
  o.x = xv.x + bv.x + bf2f(p0.x) + bf2f(p1.x);
  o.y = xv.y + bv.y + bf2f(p0.y) + bf2f(p1.y);
  o.z = xv.z + bv.z + bf2f(p0.z) + bf2f(p1.z);
  o.w = xv.w + bv.w + bf2f(p0.w) + bf2f(p1.w);
  *(float4*)(out + off) = o;
}

// ---------------- bf16 MFMA GEMM 128x128, BK=64, XCD-swizzled 1D grid ------------
template <int OUT_BF16, int RELU, int RES>
__global__ __launch_bounds__(256) void gemm_bf16(const unsigned short* __restrict__ A,
                                                 const unsigned short* __restrict__ Bt,
                                                 const float* __restrict__ bias,
                                                 const float* __restrict__ res,
                                                 void* __restrict__ C,
                                                 int M, int N, int K) {
  __shared__ unsigned short As[128 * 64];
  __shared__ unsigned short Bs[128 * 64];
  const int tid = threadIdx.x;
  const int w = tid >> 6;
  const int lane = tid & 63;

  const int nb = gridDim.x;
  const int id = blockIdx.x;
  const int lid = (id & 7) * (nb >> 3) + (id >> 3);
  const int per = (M >> 7) * 8;
  const int grp = lid / per;
  const int rem = lid - grp * per;
  const int bn = (grp * 8 + (rem & 7)) * 128;
  const int bm = (rem >> 3) * 128;

  const int wm = (w & 1) * 64, wn = (w >> 1) * 64;

  f32x4 acc[4][4];
#pragma unroll
  for (int i = 0; i < 4; ++i)
#pragma unroll
    for (int j = 0; j < 4; ++j) acc[i][j] = (f32x4){0.f, 0.f, 0.f, 0.f};

  const int srow = lane >> 3;
  const int skb = (lane & 7) ^ srow;  // swizzled source 16B-slot
  const unsigned short* Ap[4];
  const unsigned short* Bp[4];
  unsigned short* AsD[4];
  unsigned short* BsD[4];
#pragma unroll
  for (int p = 0; p < 4; ++p) {
    const int u = w * 4 + p;
    Ap[p] = A + (size_t)(bm + u * 8 + srow) * K + skb * 8;
    Bp[p] = Bt + (size_t)(bn + u * 8 + srow) * K + skb * 8;
    AsD[p] = &As[u * 512 + lane * 8];
    BsD[p] = &Bs[u * 512 + lane * 8];
  }

  const int fr = lane & 15;
  const int g = lane >> 4;
  const int sw = fr & 7;

  for (int k0 = 0; k0 < K; k0 += 64) {
    __syncthreads();
#pragma unroll
    for (int p = 0; p < 4; ++p) glds16(Ap[p] + k0, AsD[p]);
#pragma unroll
    for (int p = 0; p < 4; ++p) glds16(Bp[p] + k0, BsD[p]);
    __syncthreads();
    bf16x8 a[4][2], b[4][2];
#pragma unroll
    for (int im = 0; im < 4; ++im)
#pragma unroll
      for (int kc = 0; kc < 2; ++kc)
        a[im][kc] = *(const bf16x8*)&As[(wm + im * 16 + fr) * 64 + ((kc * 4 + g) ^ sw) * 8];
#pragma unroll
    for (int in = 0; in < 4; ++in)
#pragma unroll
      for (int kc = 0; kc < 2; ++kc)
        b[in][kc] = *(const bf16x8*)&Bs[(wn + in * 16 + fr) * 64 + ((kc * 4 + g) ^ sw) * 8];
#pragma unroll
    for (int im = 0; im < 4; ++im)
#pragma unroll
      for (int in = 0; in < 4; ++in) {
        acc[im][in] = __builtin_amdgcn_mfma_f32_16x16x32_bf16(a[im][0], b[in][0], acc[im][in], 0, 0, 0);
        acc[im][in] = __builtin_amdgcn_mfma_f32_16x16x32_bf16(a[im][1], b[in][1], acc[im][in], 0, 0, 0);
      }
  }

#pragma unroll
  for (int im = 0; im < 4; ++im) {
    const int row0 = bm + wm + im * 16 + (lane >> 4) * 4;
#pragma unroll
    for (int in = 0; in < 4; ++in) {
      const int col = bn + wn + in * 16 + fr;
      const float bv = bias[col];
#pragma unroll
      for (int r = 0; r < 4; ++r) {
        float v = acc[im][in][r] + bv;
        if (RES) v += res[(size_t)(row0 + r) * N + col];
        if (RELU) v = fmaxf(v, 0.0f);
        if (OUT_BF16)
          ((unsigned short*)C)[(size_t)(row0 + r) * N + col] = f2bf(v);
        else
          ((float*)C)[(size_t)(row0 + r) * N + col] = v;
      }
    }
  }
}

// ---------------- QKV GEMM (BK=64) with fused RoPE (Q,K) + transposed V store ----------
__global__ __launch_bounds__(256) void gemm_qkv(const unsigned short* __restrict__ A,
                                                const unsigned short* __restrict__ Bt,
                                                const float* __restrict__ bias,
                                                unsigned short* __restrict__ QKV,
                                                unsigned short* __restrict__ Vt,
                                                int M, int K) {
  __shared__ unsigned short As[128 * 64];
  __shared__ unsigned short Bs[128 * 64];
  const int tid = threadIdx.x;
  const int w = tid >> 6;
  const int lane = tid & 63;

  const int nb = gridDim.x;
  const int id = blockIdx.x;
  const int lid = (id & 7) * (nb >> 3) + (id >> 3);
  const int per = (M >> 7) * 8;
  const int grp = lid / per;
  const int rem = lid - grp * per;
  const int bn = (grp * 8 + (rem & 7)) * 128;
  const int bm = (rem >> 3) * 128;

  const int wm = (w & 1) * 64, wn = (w >> 1) * 64;

  f32x4 acc[4][4];
#pragma unroll
  for (int i = 0; i < 4; ++i)
#pragma unroll
    for (int j = 0; j < 4; ++j) acc[i][j] = (f32x4){0.f, 0.f, 0.f, 0.f};

  const int srow = lane >> 3;
  const int skb = (lane & 7) ^ srow;
  const unsigned short* Ap[4];
  const unsigned short* Bp[4];
  unsigned short* AsD[4];
  unsigned short* BsD[4];
#pragma unroll
  for (int p = 0; p < 4; ++p) {
    const int u = w * 4 + p;
    Ap[p] = A + (size_t)(bm + u * 8 + srow) * K + skb * 8;
    Bp[p] = Bt + (size_t)(bn + u * 8 + srow) * K + skb * 8;
    AsD[p] = &As[u * 512 + lane * 8];
    BsD[p] = &Bs[u * 512 + lane * 8];
  }

  const int fr = lane & 15;
  const int g = lane >> 4;
  const int sw = fr & 7;

  for (int k0 = 0; k0 < K; k0 += 64) {
    __syncthreads();
#pragma unroll
    for (int p = 0; p < 4; ++p) glds16(Ap[p] + k0, AsD[p]);
#pragma unroll
    for (int p = 0; p < 4; ++p) glds16(Bp[p] + k0, BsD[p]);
    __syncthreads();
    bf16x8 a[4][2], b[4][2];
#pragma unroll
    for (int im = 0; im < 4; ++im)
#pragma unroll
      for (int kc = 0; kc < 2; ++kc)
        a[im][kc] = *(const bf16x8*)&As[(wm + im * 16 + fr) * 64 + ((kc * 4 + g) ^ sw) * 8];
#pragma unroll
    for (int in = 0; in < 4; ++in)
#pragma unroll
      for (int kc = 0; kc < 2; ++kc)
        b[in][kc] = *(const bf16x8*)&Bs[(wn + in * 16 + fr) * 64 + ((kc * 4 + g) ^ sw) * 8];
#pragma unroll
    for (int im = 0; im < 4; ++im)
#pragma unroll
      for (int in = 0; in < 4; ++in) {
        acc[im][in] = __builtin_amdgcn_mfma_f32_16x16x32_bf16(a[im][0], b[in][0], acc[im][in], 0, 0, 0);
        acc[im][in] = __builtin_amdgcn_mfma_f32_16x16x32_bf16(a[im][1], b[in][1], acc[im][in], 0, 0, 0);
      }
  }

  const int cbase = bn + wn;
  const int seg = cbase >> 6;
  const int typ = seg >> 4;
  const int hh = seg & 15;
  const int bidx = bm >> 10;
  float bv[4];
#pragma unroll
  for (int in = 0; in < 4; ++in) bv[in] = bias[cbase + in * 16 + fr];

  if (typ == 2) {
#pragma unroll
    for (int im = 0; im < 4; ++im) {
      const int s0 = (bm & 1023) + wm + im * 16 + (lane >> 4) * 4;
#pragma unroll
      for (int in = 0; in < 4; ++in) {
        const int d = in * 16 + fr;
        ushort4 o4;
        o4.x = f2bf(acc[im][in][0] + bv[in]);
        o4.y = f2bf(acc[im][in][1] + bv[in]);
        o4.z = f2bf(acc[im][in][2] + bv[in]);
        o4.w = f2bf(acc[im][in][3] + bv[in]);
        *(ushort4*)&Vt[(size_t)((bidx * 16 + hh) * 64 + d) * S_ + s0] = o4;
      }
    }
  } else {
    const float qs = (typ == 0) ? QSCALE : 1.0f;
    const float i0 = exp2f(-LG2_10K * (float)fr);
    const float i1 = exp2f(-LG2_10K * (float)(fr + 16));
#pragma unroll
    for (int im = 0; im < 4; ++im) {
      const int row0 = bm + wm + im * 16 + (lane >> 4) * 4;
#pragma unroll
      for (int r = 0; r < 4; ++r) {
        const int row = row0 + r;
        const float s = (float)(row & 1023);
        float sn0, cs0, sn1, cs1;
        __sincosf(s * i0, &sn0, &cs0);
        __sincosf(s * i1, &sn1, &cs1);
        const float x0 = acc[im][0][r] + bv[0];
        const float x1 = acc[im][1][r] + bv[1];
        const float x2 = acc[im][2][r] + bv[2];
        const float x3 = acc[im][3][r] + bv[3];
        unsigned short* cp = QKV + (size_t)row * 3072 + cbase;
        cp[fr]      = f2bf((x0 * cs0 - x2 * sn0) * qs);
        cp[16 + fr] = f2bf((x1 * cs1 - x3 * sn1) * qs);
        cp[32 + fr] = f2bf((x2 * cs0 + x0 * sn0) * qs);
        cp[48 + fr] = f2bf((x3 * cs1 + x1 * sn1) * qs);
      }
    }
  }
}

// ---------------- MFMA flash attention v4: S^T form + double-buffered K/V staging -------
__global__ __launch_bounds__(256) void attn_v4(const unsigned short* __restrict__ QKV,
                                               const unsigned short* __restrict__ Vt,
                                               unsigned short* __restrict__ Og) {
  __shared__ unsigned short Kf[2][8 * 512];
  __shared__ unsigned short Vf[2][8 * 512];
  __shared__ unsigned short Ps[4][32 * 72];
  const int tid = threadIdx.x;
  const int w = tid >> 6, lane = tid & 63;
  const int qt = blockIdx.x, bh = blockIdx.y;
  const int b = bh >> 4, h = bh & 15;
  const int fr = lane & 15, g = lane >> 4, fk = g * 8;
  const int q0w = qt * 128 + w * 32;

  bf16x8 qB[2][2];
#pragma unroll
  for (int nt = 0; nt < 2; ++nt)
#pragma unroll
    for (int c = 0; c < 2; ++c)
      qB[nt][c] = *(const bf16x8*)&QKV[(size_t)(b * S_ + q0w + nt * 16 + fr) * 3072 +
                                       h * 64 + c * 32 + fk];

  f32x4 o[4][2];
#pragma unroll
  for (int mt = 0; mt < 4; ++mt)
#pragma unroll
    for (int nt = 0; nt < 2; ++nt) o[mt][nt] = (f32x4){0.f, 0.f, 0.f, 0.f};
  float l[2] = {0.0f, 0.0f};

#define STAGE(kt, bufi)                                                                   \
  {                                                                                       \
    _Pragma("unroll") for (int p = 0; p < 4; ++p) {                                       \
      const int u = w * 4 + p;                                                            \
      if (u < 8) {                                                                        \
        const int mt = u >> 1, c = u & 1;                                                 \
        glds16(QKV + (size_t)(b * S_ + (kt) * 64 + mt * 16 + fr) * 3072 + 1024 + h * 64 + \
                   c * 32 + fk,                                                           \
               &Kf[bufi][u * 512]);                                                       \
      } else {                                                                            \
        const int v2 = u - 8, mt = v2 >> 1, c = v2 & 1;                                   \
        glds16(Vt + (size_t)(bh * 64 + mt * 16 + fr) * S_ + (kt) * 64 + c * 32 + fk,      \
               &Vf[bufi][v2 * 512]);                                                      \
      }                                                                                   \
    }                                                                                     \
  }

  STAGE(0, 0);

  for (int kt = 0; kt < 16; ++kt) {
    __syncthreads();
    if (kt < 15) STAGE(kt + 1, (kt + 1) & 1);
    const unsigned short* Kc = Kf[kt & 1];
    const unsigned short* Vc = Vf[kt & 1];

    f32x4 s[4][2];
#pragma unroll
    for (int mt = 0; mt < 4; ++mt) {
      const bf16x8 k0 = *(const bf16x8*)&Kc[(mt * 2 + 0) * 512 + lane * 8];
      const bf16x8 k1 = *(const bf16x8*)&Kc[(mt * 2 + 1) * 512 + lane * 8];
#pragma unroll
      for (int nt = 0; nt < 2; ++nt) {
        f32x4 a = (f32x4){0.f, 0.f, 0.f, 0.f};
        a = __builtin_amdgcn_mfma_f32_16x16x32_bf16(k0, qB[nt][0], a, 0, 0, 0);
        a = __builtin_amdgcn_mfma_f32_16x16x32_bf16(k1, qB[nt][1], a, 0, 0, 0);
        s[mt][nt] = a;
      }
    }

#pragma unroll
    for (int nt = 0; nt < 2; ++nt) {
      float rs = 0.0f;
#pragma unroll
      for (int mt = 0; mt < 4; ++mt)
#pragma unroll
        for (int r = 0; r < 4; ++r) {
          const float p = exp2f(s[mt][nt][r]);
          s[mt][nt][r] = p;
          rs += p;
        }
      rs += __shfl_xor(rs, 16);
      rs += __shfl_xor(rs, 32);
      l[nt] += rs;
    }

#pragma unroll
    for (int nt = 0; nt < 2; ++nt)
#pragma unroll
      for (int mt = 0; mt < 4; ++mt) {
        uint2 pk;
        pk.x = __builtin_amdgcn_perm(fbits(s[mt][nt][1]), fbits(s[mt][nt][0]), 0x07060302u);
        pk.y = __builtin_amdgcn_perm(fbits(s[mt][nt][3]), fbits(s[mt][nt][2]), 0x07060302u);
        *(uint2*)&Ps[w][(nt * 16 + fr) * 72 + mt * 16 + g * 4] = pk;
      }

    bf16x8 pB[2][2];
#pragma unroll
    for (int nt = 0; nt < 2; ++nt)
#pragma unroll
      for (int c = 0; c < 2; ++c)
        pB[nt][c] = *(const bf16x8*)&Ps[w][(nt * 16 + fr) * 72 + c * 32 + fk];
#pragma unroll
    for (int mt = 0; mt < 4; ++mt) {
      const bf16x8 v0 = *(const bf16x8*)&Vc[(mt * 2 + 0) * 512 + lane * 8];
      const bf16x8 v1 = *(const bf16x8*)&Vc[(mt * 2 + 1) * 512 + lane * 8];
#pragma unroll
      for (int nt = 0; nt < 2; ++nt) {
        o[mt][nt] = __builtin_amdgcn_mfma_f32_16x16x32_bf16(v0, pB[nt][0], o[mt][nt], 0, 0, 0);
        o[mt][nt] = __builtin_amdgcn_mfma_f32_16x16x32_bf16(v1, pB[nt][1], o[mt][nt], 0, 0, 0);
      }
    }
  }

  const float linv0 = 1.0f / l[0], linv1 = 1.0f / l[1];
#pragma unroll
  for (int nt = 0; nt < 2; ++nt) {
    const float li = nt ? linv1 : linv0;
#pragma unroll
    for (int mt = 0; mt < 4; ++mt) {
      uint2 pk;
      pk.x = __builtin_amdgcn_perm(fbits(o[mt][nt][1] * li), fbits(o[mt][nt][0] * li), 0x07060302u);
      pk.y = __builtin_amdgcn_perm(fbits(o[mt][nt][3] * li), fbits(o[mt][nt][2] * li), 0x07060302u);
      *(uint2*)&Ps[w][(nt * 16 + fr) * 72 + mt * 16 + g * 4] = pk;
    }
  }
  const int qr = lane >> 1, hf = lane & 1;
#pragma unroll
  for (int c = 0; c < 2; ++c) {
    const bf16x8 vv = *(const bf16x8*)&Ps[w][qr * 72 + hf * 16 + c * 32];
    *(bf16x8*)&Og[(size_t)(b * S_ + q0w + qr) * E_ + h * 64 + hf * 16 + c * 32] = vv;
  }
}

extern "C" void kernel_launch(void* const* d_in, const int* in_sizes, int n_in,
                              void* d_out, int out_size, void* d_ws, size_t ws_size,
                              hipStream_t stream) {
  const float* x  = (const float*)d_in[0];
  const float* WQ = (const float*)d_in[1];
  const float* bQ = (const float*)d_in[2];
  const float* WK = (const float*)d_in[3];
  const float* bK = (const float*)d_in[4];
  const float* WV = (const float*)d_in[5];
  const float* bV = (const float*)d_in[6];
  const float* WO = (const float*)d_in[7];
  const float* bO = (const float*)d_in[8];
  const float* W1 = (const float*)d_in[9];
  const float* b1 = (const float*)d_in[10];
  const float* W2 = (const float*)d_in[11];
  const float* b2 = (const float*)d_in[12];
  const float* g1 = (const float*)d_in[13];
  const float* g2 = (const float*)d_in[14];
  float* out = (float*)d_out;

  char* ws = (char*)d_ws;
  const size_t MB = 1024 * 1024;
  unsigned short* h1   = (unsigned short*)(ws + 0 * MB);
  unsigned short* QKV  = (unsigned short*)(ws + 16 * MB);   // [8192,3072]
  unsigned short* Vt   = (unsigned short*)(ws + 64 * MB);   // [128*64,1024]
  unsigned short* Ob   = (unsigned short*)(ws + 80 * MB);
  float*          x1   = (float*)(ws + 96 * MB);
  unsigned short* h2   = (unsigned short*)(ws + 128 * MB);
  unsigned short* mid  = (unsigned short*)(ws + 16 * MB);   // reuses QKV+Vt region
  unsigned short* WQKVt= (unsigned short*)(ws + 144 * MB);
  unsigned short* WOt  = (unsigned short*)(ws + 150 * MB);
  unsigned short* W1t  = (unsigned short*)(ws + 152 * MB);
  unsigned short* W2t  = (unsigned short*)(ws + 160 * MB);
  float*          bqkv = (float*)(ws + 168 * MB);
  unsigned short* Pp   = (unsigned short*)(ws + 176 * MB);  // [2][8192,1024] bf16 partials

  const int M = B_ * S_;

  prep<<<12300, 256, 0, stream>>>(WQ, WK, WV, WO, W1, W2, bQ, bK, bV,
                                  WQKVt, WOt, W1t, W2t, bqkv);

  rmsnorm_kernel<<<M, 256, 0, stream>>>(x, g1, h1);

  gemm_qkv<<<24 * 64, 256, 0, stream>>>(h1, WQKVt, bqkv, QKV, Vt, M, E_);

  attn_v4<<<dim3(8, B_ * H_), 256, 0, stream>>>(QKV, Vt, Ob);

  // O-proj: 128x128 tile, res-add x, fp32 out
  gemm_bf16<0, 0, 1><<<64 * 8, 256, 0, stream>>>(Ob, WOt, bO, x, x1, M, E_, E_);

  rmsnorm_kernel<<<M, 256, 0, stream>>>(x1, g2, h2);

  // FF1: 8-phase (512,1) 256x256 tiles — A/B vs R6's coarse 81.9us
  gemm8p<0, 0><<<512, 512, 0, stream>>>(h2, W1t, b1, mid, M, FF_, E_);

  // FF2: 8-phase (512,1), split-K=2 (R6-proven < 81.3us)
  gemm8p<1, 1><<<256, 512, 0, stream>>>(mid, W2t, nullptr, Pp, M, 1024, 4096);

  ff2_reduce<<<8192, 256, 0, stream>>>(Pp, x1, b2, out);
}

// Round 8
// 486.110 us; speedup vs baseline: 1.0487x; 1.0487x over previous
//
#include <hip/hip_runtime.h>
#include <math.h>

#define B_ 8
#define S_ 1024
#define E_ 1024
#define H_ 16
#define FF_ 4096

typedef __attribute__((ext_vector_type(8))) short bf16x8;
typedef __attribute__((ext_vector_type(4))) float f32x4;

#define QSCALE 0.1803368801111f  // 0.125 * log2(e)
#define LG2_10K 0.4152410118f    // log2(10000)/32

__device__ __forceinline__ unsigned short f2bf(float f) {
  union { float f; unsigned u; } v;
  v.f = f;
  unsigned r = v.u + 0x7fffu + ((v.u >> 16) & 1u);
  return (unsigned short)(r >> 16);
}
__device__ __forceinline__ float bf2f(unsigned short u) {
  union { unsigned u; float f; } v;
  v.u = ((unsigned)u) << 16;
  return v.f;
}
__device__ __forceinline__ unsigned fbits(float f) {
  union { float f; unsigned u; } v;
  v.f = f;
  return v.u;
}

__device__ __forceinline__ void glds16(const void* g, void* l) {
  __builtin_amdgcn_global_load_lds(
      (const __attribute__((address_space(1))) unsigned int*)g,
      (__attribute__((address_space(3))) unsigned int*)l, 16, 0, 0);
}

// ---------------- prep: all weight converts (fp32 [K][N] -> bf16 [N][K]) + bias pack ----
__global__ __launch_bounds__(256) void prep(const float* __restrict__ WQ,
                                            const float* __restrict__ WK,
                                            const float* __restrict__ WV,
                                            const float* __restrict__ WO,
                                            const float* __restrict__ W1,
                                            const float* __restrict__ W2,
                                            const float* __restrict__ bQ,
                                            const float* __restrict__ bK,
                                            const float* __restrict__ bV,
                                            unsigned short* __restrict__ WQKVt,
                                            unsigned short* __restrict__ WOt,
                                            unsigned short* __restrict__ W1t,
                                            unsigned short* __restrict__ W2t,
                                            float* __restrict__ bqkv) {
  const int id = blockIdx.x;
  if (id >= 12288) {
    const int i = (id - 12288) * 256 + threadIdx.x;
    if (i < 3072)
      bqkv[i] = (i < 1024) ? bQ[i] : ((i < 2048) ? bK[i - 1024] : bV[i - 2048]);
    return;
  }
  const float* W;
  unsigned short* D;
  int K, N, x, y;
  if (id < 4096) {
    const int m = id >> 10;
    const float* ws4[4] = {WQ, WK, WV, WO};
    unsigned short* ds4[4] = {WQKVt, WQKVt + 1024 * 1024, WQKVt + 2 * 1024 * 1024, WOt};
    W = ws4[m]; D = ds4[m]; K = 1024; N = 1024;
    x = id & 31; y = (id >> 5) & 31;
  } else if (id < 8192) {
    const int j = id - 4096;
    W = W1; D = W1t; K = 1024; N = 4096;
    x = j & 127; y = j >> 7;
  } else {
    const int j = id - 8192;
    W = W2; D = W2t; K = 4096; N = 1024;
    x = j & 31; y = j >> 5;
  }
  __shared__ float t[32][33];
  const int tx = threadIdx.x & 31, ty = threadIdx.x >> 5;
  const int n0 = x * 32, k0 = y * 32;
#pragma unroll
  for (int p = 0; p < 4; ++p)
    t[ty + p * 8][tx] = W[(size_t)(k0 + ty + p * 8) * N + n0 + tx];
  __syncthreads();
#pragma unroll
  for (int p = 0; p < 4; ++p)
    D[(size_t)(n0 + ty + p * 8) * K + k0 + tx] = f2bf(t[tx][ty + p * 8]);
}

// ---------------- RMSNorm: fp32 in, bf16 out; one block per row ----------------
__global__ __launch_bounds__(256) void rmsnorm_kernel(const float* __restrict__ x,
                                                      const float* __restrict__ g,
                                                      unsigned short* __restrict__ out) {
  const int row = blockIdx.x;
  const int t = threadIdx.x;
  const float4 v = ((const float4*)(x + (size_t)row * E_))[t];
  float ss = v.x * v.x + v.y * v.y + v.z * v.z + v.w * v.w;
#pragma unroll
  for (int off = 32; off > 0; off >>= 1) ss += __shfl_down(ss, off);
  __shared__ float sred[4];
  if ((t & 63) == 0) sred[t >> 6] = ss;
  __syncthreads();
  const float tot = sred[0] + sred[1] + sred[2] + sred[3];
  const float rinv = rsqrtf(tot * (1.0f / E_) + 1.1920929e-07f);
  const float4 gv = ((const float4*)g)[t];
  ushort4 o;
  o.x = f2bf(v.x * rinv * gv.x);
  o.y = f2bf(v.y * rinv * gv.y);
  o.z = f2bf(v.z * rinv * gv.z);
  o.w = f2bf(v.w * rinv * gv.w);
  ((ushort4*)(out + (size_t)row * E_))[t] = o;
}

// ======== 256x256 BK=64 coarse counted-vmcnt GEMM (R3/R6-proven: 81.5 us, no spill) ====
// LDS unit = 1024 B = 8 rows x 128 B. Lane l of a unit: row r = l>>3, phys 16B slot
// s = l&7 holds logical k-slot (s ^ r); source address pre-swizzled, LDS dest linear.
// Pipeline: tiles t, t+1 staged; compute t with vmcnt(8) (t+1's 8 loads stay in
// flight across barriers); issue t+2 into buf[t&1] after the post-compute barrier.
// NOTE: 8-phase variants (R4/R5/R7) all lost to this coarse schedule here —
// the compiler pins VGPR at 128 for 512-thr blocks and spills acc (+20-29MB
// scratch). Do not revisit without a fix for the allocation.
template <int EPI, int SPLIT>
__global__ __launch_bounds__(512, 2) void gemm256(const unsigned short* __restrict__ A,
                                                  const unsigned short* __restrict__ Bt,
                                                  const float* __restrict__ bias,
                                                  unsigned short* __restrict__ C,
                                                  int M, int N, int K) {
  __shared__ unsigned short Ls[2][2][256 * 64];  // [buf][A/B][rows*k] = 128 KiB
  const int tid = threadIdx.x;
  const int w = tid >> 6;
  const int lane = tid & 63;

  int id = blockIdx.x;
  int kh = 0;
  int nb = gridDim.x;
  if (SPLIT) { kh = id >> 7; id &= 127; nb = 128; }
  const int lid = (id & 7) * (nb >> 3) + (id >> 3);
  const int nbn = N >> 8;
  const int bm = (lid / nbn) * 256;
  const int bn = (lid % nbn) * 256;

  const int Kloc = SPLIT ? (K >> 1) : K;
  const unsigned short* Ab = A + (size_t)kh * Kloc;
  const unsigned short* Bb = Bt + (size_t)kh * Kloc;

  const int wm = (w & 1) * 128, wn = (w >> 1) * 64;

  f32x4 acc[8][4];
#pragma unroll
  for (int i = 0; i < 8; ++i)
#pragma unroll
    for (int j = 0; j < 4; ++j) acc[i][j] = (f32x4){0.f, 0.f, 0.f, 0.f};

  const int srow = lane >> 3;
  const int skb = (lane & 7) ^ srow;  // pre-swizzled source 16B slot
  const unsigned short* Ap[4];
  const unsigned short* Bp[4];
#pragma unroll
  for (int p = 0; p < 4; ++p) {
    const int u = w * 4 + p;  // unit 0..31 (8 rows each)
    Ap[p] = Ab + (size_t)(bm + u * 8 + srow) * K + skb * 8;
    Bp[p] = Bb + (size_t)(bn + u * 8 + srow) * K + skb * 8;
  }

  const int fr = lane & 15;
  const int g = lane >> 4;
  const int sw = fr & 7;

#define ISSUE256(tt, bi)                                              \
  {                                                                   \
    _Pragma("unroll") for (int p = 0; p < 4; ++p) {                   \
      const int u = w * 4 + p;                                        \
      glds16(Ap[p] + (size_t)(tt) * 64, &Ls[bi][0][u * 512 + lane * 8]); \
    }                                                                 \
    _Pragma("unroll") for (int p = 0; p < 4; ++p) {                   \
      const int u = w * 4 + p;                                        \
      glds16(Bp[p] + (size_t)(tt) * 64, &Ls[bi][1][u * 512 + lane * 8]); \
    }                                                                 \
  }

  const int nt = Kloc >> 6;
  ISSUE256(0, 0);
  ISSUE256(1, 1);

  for (int t = 0; t < nt; ++t) {
    if (t < nt - 1)
      asm volatile("s_waitcnt vmcnt(8)" ::: "memory");
    else
      asm volatile("s_waitcnt vmcnt(0)" ::: "memory");
    __builtin_amdgcn_s_barrier();
    __builtin_amdgcn_sched_barrier(0);

    const unsigned short* Ac = &Ls[t & 1][0][0];
    const unsigned short* Bc = &Ls[t & 1][1][0];
#pragma unroll
    for (int kc = 0; kc < 2; ++kc) {
      bf16x8 a[8], b[4];
#pragma unroll
      for (int im = 0; im < 8; ++im)
        a[im] = *(const bf16x8*)&Ac[(wm + im * 16 + fr) * 64 + (((kc * 4 + g) ^ sw)) * 8];
#pragma unroll
      for (int in = 0; in < 4; ++in)
        b[in] = *(const bf16x8*)&Bc[(wn + in * 16 + fr) * 64 + (((kc * 4 + g) ^ sw)) * 8];
      __builtin_amdgcn_s_setprio(1);
#pragma unroll
      for (int im = 0; im < 8; ++im)
#pragma unroll
        for (int in = 0; in < 4; ++in)
          acc[im][in] = __builtin_amdgcn_mfma_f32_16x16x32_bf16(a[im], b[in], acc[im][in], 0, 0, 0);
      __builtin_amdgcn_s_setprio(0);
    }

    __builtin_amdgcn_sched_barrier(0);
    __builtin_amdgcn_s_barrier();
    if (t + 2 < nt) ISSUE256(t + 2, t & 1);
  }

  if (EPI == 0) {
#pragma unroll
    for (int im = 0; im < 8; ++im) {
      const int row0 = bm + wm + im * 16 + g * 4;
#pragma unroll
      for (int in = 0; in < 4; ++in) {
        const int col = bn + wn + in * 16 + fr;
        const float bv = bias[col];
#pragma unroll
        for (int r = 0; r < 4; ++r) {
          float v = acc[im][in][r] + bv;
          v = fmaxf(v, 0.0f);
          C[(size_t)(row0 + r) * N + col] = f2bf(v);
        }
      }
    }
  } else {
    unsigned short* P = C + (size_t)kh * ((size_t)M * N);
#pragma unroll
    for (int im = 0; im < 8; ++im) {
      const int row0 = bm + wm + im * 16 + g * 4;
#pragma unroll
      for (int in = 0; in < 4; ++in) {
        const int col = bn + wn + in * 16 + fr;
#pragma unroll
        for (int r = 0; r < 4; ++r)
          P[(size_t)(row0 + r) * N + col] = f2bf(acc[im][in][r]);
      }
    }
  }
#undef ISSUE256
}

// ---------------- bf16 MFMA GEMM 128x128, BK=64, XCD-swizzled 1D grid ------------
// R1-proven ~800 TF. Used for O-proj (res=x) and single-pass FF2 (res=x1, fp32 out).
template <int OUT_BF16, int RELU, int RES>
__global__ __launch_bounds__(256) void gemm_bf16(const unsigned short* __restrict__ A,
                                                 const unsigned short* __restrict__ Bt,
                                                 const float* __restrict__ bias,
                                                 const float* __restrict__ res,
                                                 void* __restrict__ C,
                                                 int M, int N, int K) {
  __shared__ unsigned short As[128 * 64];
  __shared__ unsigned short Bs[128 * 64];
  const int tid = threadIdx.x;
  const int w = tid >> 6;
  const int lane = tid & 63;

  const int nb = gridDim.x;
  const int id = blockIdx.x;
  const int lid = (id & 7) * (nb >> 3) + (id >> 3);
  const int per = (M >> 7) * 8;
  const int grp = lid / per;
  const int rem = lid - grp * per;
  const int bn = (grp * 8 + (rem & 7)) * 128;
  const int bm = (rem >> 3) * 128;

  const int wm = (w & 1) * 64, wn = (w >> 1) * 64;

  f32x4 acc[4][4];
#pragma unroll
  for (int i = 0; i < 4; ++i)
#pragma unroll
    for (int j = 0; j < 4; ++j) acc[i][j] = (f32x4){0.f, 0.f, 0.f, 0.f};

  const int srow = lane >> 3;
  const int skb = (lane & 7) ^ srow;  // swizzled source 16B-slot
  const unsigned short* Ap[4];
  const unsigned short* Bp[4];
  unsigned short* AsD[4];
  unsigned short* BsD[4];
#pragma unroll
  for (int p = 0; p < 4; ++p) {
    const int u = w * 4 + p;
    Ap[p] = A + (size_t)(bm + u * 8 + srow) * K + skb * 8;
    Bp[p] = Bt + (size_t)(bn + u * 8 + srow) * K + skb * 8;
    AsD[p] = &As[u * 512 + lane * 8];
    BsD[p] = &Bs[u * 512 + lane * 8];
  }

  const int fr = lane & 15;
  const int g = lane >> 4;
  const int sw = fr & 7;

  for (int k0 = 0; k0 < K; k0 += 64) {
    __syncthreads();
#pragma unroll
    for (int p = 0; p < 4; ++p) glds16(Ap[p] + k0, AsD[p]);
#pragma unroll
    for (int p = 0; p < 4; ++p) glds16(Bp[p] + k0, BsD[p]);
    __syncthreads();
    bf16x8 a[4][2], b[4][2];
#pragma unroll
    for (int im = 0; im < 4; ++im)
#pragma unroll
      for (int kc = 0; kc < 2; ++kc)
        a[im][kc] = *(const bf16x8*)&As[(wm + im * 16 + fr) * 64 + ((kc * 4 + g) ^ sw) * 8];
#pragma unroll
    for (int in = 0; in < 4; ++in)
#pragma unroll
      for (int kc = 0; kc < 2; ++kc)
        b[in][kc] = *(const bf16x8*)&Bs[(wn + in * 16 + fr) * 64 + ((kc * 4 + g) ^ sw) * 8];
#pragma unroll
    for (int im = 0; im < 4; ++im)
#pragma unroll
      for (int in = 0; in < 4; ++in) {
        acc[im][in] = __builtin_amdgcn_mfma_f32_16x16x32_bf16(a[im][0], b[in][0], acc[im][in], 0, 0, 0);
        acc[im][in] = __builtin_amdgcn_mfma_f32_16x16x32_bf16(a[im][1], b[in][1], acc[im][in], 0, 0, 0);
      }
  }

#pragma unroll
  for (int im = 0; im < 4; ++im) {
    const int row0 = bm + wm + im * 16 + (lane >> 4) * 4;
#pragma unroll
    for (int in = 0; in < 4; ++in) {
      const int col = bn + wn + in * 16 + fr;
      const float bv = bias[col];
#pragma unroll
      for (int r = 0; r < 4; ++r) {
        float v = acc[im][in][r] + bv;
        if (RES) v += res[(size_t)(row0 + r) * N + col];
        if (RELU) v = fmaxf(v, 0.0f);
        if (OUT_BF16)
          ((unsigned short*)C)[(size_t)(row0 + r) * N + col] = f2bf(v);
        else
          ((float*)C)[(size_t)(row0 + r) * N + col] = v;
      }
    }
  }
}

// ---------------- QKV GEMM (BK=64) with fused RoPE (Q,K) + transposed V store ----------
__global__ __launch_bounds__(256) void gemm_qkv(const unsigned short* __restrict__ A,
                                                const unsigned short* __restrict__ Bt,
                                                const float* __restrict__ bias,
                                                unsigned short* __restrict__ QKV,
                                                unsigned short* __restrict__ Vt,
                                                int M, int K) {
  __shared__ unsigned short As[128 * 64];
  __shared__ unsigned short Bs[128 * 64];
  const int tid = threadIdx.x;
  const int w = tid >> 6;
  const int lane = tid & 63;

  const int nb = gridDim.x;
  const int id = blockIdx.x;
  const int lid = (id & 7) * (nb >> 3) + (id >> 3);
  const int per = (M >> 7) * 8;
  const int grp = lid / per;
  const int rem = lid - grp * per;
  const int bn = (grp * 8 + (rem & 7)) * 128;
  const int bm = (rem >> 3) * 128;

  const int wm = (w & 1) * 64, wn = (w >> 1) * 64;

  f32x4 acc[4][4];
#pragma unroll
  for (int i = 0; i < 4; ++i)
#pragma unroll
    for (int j = 0; j < 4; ++j) acc[i][j] = (f32x4){0.f, 0.f, 0.f, 0.f};

  const int srow = lane >> 3;
  const int skb = (lane & 7) ^ srow;
  const unsigned short* Ap[4];
  const unsigned short* Bp[4];
  unsigned short* AsD[4];
  unsigned short* BsD[4];
#pragma unroll
  for (int p = 0; p < 4; ++p) {
    const int u = w * 4 + p;
    Ap[p] = A + (size_t)(bm + u * 8 + srow) * K + skb * 8;
    Bp[p] = Bt + (size_t)(bn + u * 8 + srow) * K + skb * 8;
    AsD[p] = &As[u * 512 + lane * 8];
    BsD[p] = &Bs[u * 512 + lane * 8];
  }

  const int fr = lane & 15;
  const int g = lane >> 4;
  const int sw = fr & 7;

  for (int k0 = 0; k0 < K; k0 += 64) {
    __syncthreads();
#pragma unroll
    for (int p = 0; p < 4; ++p) glds16(Ap[p] + k0, AsD[p]);
#pragma unroll
    for (int p = 0; p < 4; ++p) glds16(Bp[p] + k0, BsD[p]);
    __syncthreads();
    bf16x8 a[4][2], b[4][2];
#pragma unroll
    for (int im = 0; im < 4; ++im)
#pragma unroll
      for (int kc = 0; kc < 2; ++kc)
        a[im][kc] = *(const bf16x8*)&As[(wm + im * 16 + fr) * 64 + ((kc * 4 + g) ^ sw) * 8];
#pragma unroll
    for (int in = 0; in < 4; ++in)
#pragma unroll
      for (int kc = 0; kc < 2; ++kc)
        b[in][kc] = *(const bf16x8*)&Bs[(wn + in * 16 + fr) * 64 + ((kc * 4 + g) ^ sw) * 8];
#pragma unroll
    for (int im = 0; im < 4; ++im)
#pragma unroll
      for (int in = 0; in < 4; ++in) {
        acc[im][in] = __builtin_amdgcn_mfma_f32_16x16x32_bf16(a[im][0], b[in][0], acc[im][in], 0, 0, 0);
        acc[im][in] = __builtin_amdgcn_mfma_f32_16x16x32_bf16(a[im][1], b[in][1], acc[im][in], 0, 0, 0);
      }
  }

  const int cbase = bn + wn;
  const int seg = cbase >> 6;
  const int typ = seg >> 4;
  const int hh = seg & 15;
  const int bidx = bm >> 10;
  float bv[4];
#pragma unroll
  for (int in = 0; in < 4; ++in) bv[in] = bias[cbase + in * 16 + fr];

  if (typ == 2) {
#pragma unroll
    for (int im = 0; im < 4; ++im) {
      const int s0 = (bm & 1023) + wm + im * 16 + (lane >> 4) * 4;
#pragma unroll
      for (int in = 0; in < 4; ++in) {
        const int d = in * 16 + fr;
        ushort4 o4;
        o4.x = f2bf(acc[im][in][0] + bv[in]);
        o4.y = f2bf(acc[im][in][1] + bv[in]);
        o4.z = f2bf(acc[im][in][2] + bv[in]);
        o4.w = f2bf(acc[im][in][3] + bv[in]);
        *(ushort4*)&Vt[(size_t)((bidx * 16 + hh) * 64 + d) * S_ + s0] = o4;
      }
    }
  } else {
    const float qs = (typ == 0) ? QSCALE : 1.0f;
    const float i0 = exp2f(-LG2_10K * (float)fr);
    const float i1 = exp2f(-LG2_10K * (float)(fr + 16));
#pragma unroll
    for (int im = 0; im < 4; ++im) {
      const int row0 = bm + wm + im * 16 + (lane >> 4) * 4;
#pragma unroll
      for (int r = 0; r < 4; ++r) {
        const int row = row0 + r;
        const float s = (float)(row & 1023);
        float sn0, cs0, sn1, cs1;
        __sincosf(s * i0, &sn0, &cs0);
        __sincosf(s * i1, &sn1, &cs1);
        const float x0 = acc[im][0][r] + bv[0];
        const float x1 = acc[im][1][r] + bv[1];
        const float x2 = acc[im][2][r] + bv[2];
        const float x3 = acc[im][3][r] + bv[3];
        unsigned short* cp = QKV + (size_t)row * 3072 + cbase;
        cp[fr]      = f2bf((x0 * cs0 - x2 * sn0) * qs);
        cp[16 + fr] = f2bf((x1 * cs1 - x3 * sn1) * qs);
        cp[32 + fr] = f2bf((x2 * cs0 + x0 * sn0) * qs);
        cp[48 + fr] = f2bf((x3 * cs1 + x1 * sn1) * qs);
      }
    }
  }
}

// ---------------- MFMA flash attention v4: S^T form + double-buffered K/V staging -------
__global__ __launch_bounds__(256) void attn_v4(const unsigned short* __restrict__ QKV,
                                               const unsigned short* __restrict__ Vt,
                                               unsigned short* __restrict__ Og) {
  __shared__ unsigned short Kf[2][8 * 512];
  __shared__ unsigned short Vf[2][8 * 512];
  __shared__ unsigned short Ps[4][32 * 72];
  const int tid = threadIdx.x;
  const int w = tid >> 6, lane = tid & 63;
  const int qt = blockIdx.x, bh = blockIdx.y;
  const int b = bh >> 4, h = bh & 15;
  const int fr = lane & 15, g = lane >> 4, fk = g * 8;
  const int q0w = qt * 128 + w * 32;

  bf16x8 qB[2][2];
#pragma unroll
  for (int nt = 0; nt < 2; ++nt)
#pragma unroll
    for (int c = 0; c < 2; ++c)
      qB[nt][c] = *(const bf16x8*)&QKV[(size_t)(b * S_ + q0w + nt * 16 + fr) * 3072 +
                                       h * 64 + c * 32 + fk];

  f32x4 o[4][2];
#pragma unroll
  for (int mt = 0; mt < 4; ++mt)
#pragma unroll
    for (int nt = 0; nt < 2; ++nt) o[mt][nt] = (f32x4){0.f, 0.f, 0.f, 0.f};
  float l[2] = {0.0f, 0.0f};

#define STAGE(kt, bufi)                                                                   \
  {                                                                                       \
    _Pragma("unroll") for (int p = 0; p < 4; ++p) {                                       \
      const int u = w * 4 + p;                                                            \
      if (u < 8) {                                                                        \
        const int mt = u >> 1, c = u & 1;                                                 \
        glds16(QKV + (size_t)(b * S_ + (kt) * 64 + mt * 16 + fr) * 3072 + 1024 + h * 64 + \
                   c * 32 + fk,                                                           \
               &Kf[bufi][u * 512]);                                                       \
      } else {                                                                            \
        const int v2 = u - 8, mt = v2 >> 1, c = v2 & 1;                                   \
        glds16(Vt + (size_t)(bh * 64 + mt * 16 + fr) * S_ + (kt) * 64 + c * 32 + fk,      \
               &Vf[bufi][v2 * 512]);                                                      \
      }                                                                                   \
    }                                                                                     \
  }

  STAGE(0, 0);

  for (int kt = 0; kt < 16; ++kt) {
    __syncthreads();
    if (kt < 15) STAGE(kt + 1, (kt + 1) & 1);
    const unsigned short* Kc = Kf[kt & 1];
    const unsigned short* Vc = Vf[kt & 1];

    f32x4 s[4][2];
#pragma unroll
    for (int mt = 0; mt < 4; ++mt) {
      const bf16x8 k0 = *(const bf16x8*)&Kc[(mt * 2 + 0) * 512 + lane * 8];
      const bf16x8 k1 = *(const bf16x8*)&Kc[(mt * 2 + 1) * 512 + lane * 8];
#pragma unroll
      for (int nt = 0; nt < 2; ++nt) {
        f32x4 a = (f32x4){0.f, 0.f, 0.f, 0.f};
        a = __builtin_amdgcn_mfma_f32_16x16x32_bf16(k0, qB[nt][0], a, 0, 0, 0);
        a = __builtin_amdgcn_mfma_f32_16x16x32_bf16(k1, qB[nt][1], a, 0, 0, 0);
        s[mt][nt] = a;
      }
    }

#pragma unroll
    for (int nt = 0; nt < 2; ++nt) {
      float rs = 0.0f;
#pragma unroll
      for (int mt = 0; mt < 4; ++mt)
#pragma unroll
        for (int r = 0; r < 4; ++r) {
          const float p = exp2f(s[mt][nt][r]);
          s[mt][nt][r] = p;
          rs += p;
        }
      rs += __shfl_xor(rs, 16);
      rs += __shfl_xor(rs, 32);
      l[nt] += rs;
    }

#pragma unroll
    for (int nt = 0; nt < 2; ++nt)
#pragma unroll
      for (int mt = 0; mt < 4; ++mt) {
        uint2 pk;
        pk.x = __builtin_amdgcn_perm(fbits(s[mt][nt][1]), fbits(s[mt][nt][0]), 0x07060302u);
        pk.y = __builtin_amdgcn_perm(fbits(s[mt][nt][3]), fbits(s[mt][nt][2]), 0x07060302u);
        *(uint2*)&Ps[w][(nt * 16 + fr) * 72 + mt * 16 + g * 4] = pk;
      }

    bf16x8 pB[2][2];
#pragma unroll
    for (int nt = 0; nt < 2; ++nt)
#pragma unroll
      for (int c = 0; c < 2; ++c)
        pB[nt][c] = *(const bf16x8*)&Ps[w][(nt * 16 + fr) * 72 + c * 32 + fk];
#pragma unroll
    for (int mt = 0; mt < 4; ++mt) {
      const bf16x8 v0 = *(const bf16x8*)&Vc[(mt * 2 + 0) * 512 + lane * 8];
      const bf16x8 v1 = *(const bf16x8*)&Vc[(mt * 2 + 1) * 512 + lane * 8];
#pragma unroll
      for (int nt = 0; nt < 2; ++nt) {
        o[mt][nt] = __builtin_amdgcn_mfma_f32_16x16x32_bf16(v0, pB[nt][0], o[mt][nt], 0, 0, 0);
        o[mt][nt] = __builtin_amdgcn_mfma_f32_16x16x32_bf16(v1, pB[nt][1], o[mt][nt], 0, 0, 0);
      }
    }
  }

  const float linv0 = 1.0f / l[0], linv1 = 1.0f / l[1];
#pragma unroll
  for (int nt = 0; nt < 2; ++nt) {
    const float li = nt ? linv1 : linv0;
#pragma unroll
    for (int mt = 0; mt < 4; ++mt) {
      uint2 pk;
      pk.x = __builtin_amdgcn_perm(fbits(o[mt][nt][1] * li), fbits(o[mt][nt][0] * li), 0x07060302u);
      pk.y = __builtin_amdgcn_perm(fbits(o[mt][nt][3] * li), fbits(o[mt][nt][2] * li), 0x07060302u);
      *(uint2*)&Ps[w][(nt * 16 + fr) * 72 + mt * 16 + g * 4] = pk;
    }
  }
  const int qr = lane >> 1, hf = lane & 1;
#pragma unroll
  for (int c = 0; c < 2; ++c) {
    const bf16x8 vv = *(const bf16x8*)&Ps[w][qr * 72 + hf * 16 + c * 32];
    *(bf16x8*)&Og[(size_t)(b * S_ + q0w + qr) * E_ + h * 64 + hf * 16 + c * 32] = vv;
  }
}

extern "C" void kernel_launch(void* const* d_in, const int* in_sizes, int n_in,
                              void* d_out, int out_size, void* d_ws, size_t ws_size,
                              hipStream_t stream) {
  const float* x  = (const float*)d_in[0];
  const float* WQ = (const float*)d_in[1];
  const float* bQ = (const float*)d_in[2];
  const float* WK = (const float*)d_in[3];
  const float* bK = (const float*)d_in[4];
  const float* WV = (const float*)d_in[5];
  const float* bV = (const float*)d_in[6];
  const float* WO = (const float*)d_in[7];
  const float* bO = (const float*)d_in[8];
  const float* W1 = (const float*)d_in[9];
  const float* b1 = (const float*)d_in[10];
  const float* W2 = (const float*)d_in[11];
  const float* b2 = (const float*)d_in[12];
  const float* g1 = (const float*)d_in[13];
  const float* g2 = (const float*)d_in[14];
  float* out = (float*)d_out;

  char* ws = (char*)d_ws;
  const size_t MB = 1024 * 1024;
  unsigned short* h1   = (unsigned short*)(ws + 0 * MB);
  unsigned short* QKV  = (unsigned short*)(ws + 16 * MB);   // [8192,3072]
  unsigned short* Vt   = (unsigned short*)(ws + 64 * MB);   // [128*64,1024]
  unsigned short* Ob   = (unsigned short*)(ws + 80 * MB);
  float*          x1   = (float*)(ws + 96 * MB);
  unsigned short* h2   = (unsigned short*)(ws + 128 * MB);
  unsigned short* mid  = (unsigned short*)(ws + 16 * MB);   // reuses QKV+Vt region
  unsigned short* WQKVt= (unsigned short*)(ws + 144 * MB);
  unsigned short* WOt  = (unsigned short*)(ws + 150 * MB);
  unsigned short* W1t  = (unsigned short*)(ws + 152 * MB);
  unsigned short* W2t  = (unsigned short*)(ws + 160 * MB);
  float*          bqkv = (float*)(ws + 168 * MB);

  const int M = B_ * S_;

  prep<<<12300, 256, 0, stream>>>(WQ, WK, WV, WO, W1, W2, bQ, bK, bV,
                                  WQKVt, WOt, W1t, W2t, bqkv);

  rmsnorm_kernel<<<M, 256, 0, stream>>>(x, g1, h1);

  gemm_qkv<<<24 * 64, 256, 0, stream>>>(h1, WQKVt, bqkv, QKV, Vt, M, E_);

  attn_v4<<<dim3(8, B_ * H_), 256, 0, stream>>>(QKV, Vt, Ob);

  // O-proj: 128x128 tile, res-add x, fp32 out
  gemm_bf16<0, 0, 1><<<64 * 8, 256, 0, stream>>>(Ob, WOt, bO, x, x1, M, E_, E_);

  rmsnorm_kernel<<<M, 256, 0, stream>>>(x1, g2, h2);

  // FF1: coarse counted-vmcnt 256x256 (R3/R6-proven 81.5us)
  gemm256<0, 0><<<512, 512, 0, stream>>>(h2, W1t, b1, mid, M, FF_, E_);

  // FF2: single-pass 128x128, K=4096, fused res(x1)+bias(b2), fp32 out.
  // Replaces split-K partials + ff2_reduce (saves ~96MB partial HBM traffic + a launch).
  gemm_bf16<0, 0, 1><<<64 * 8, 256, 0, stream>>>(mid, W2t, b2, x1, out, M, E_, FF_);
}

// Round 9
// 474.573 us; speedup vs baseline: 1.0742x; 1.0243x over previous
//
#include <hip/hip_runtime.h>
#include <math.h>

#define B_ 8
#define S_ 1024
#define E_ 1024
#define H_ 16
#define FF_ 4096

typedef __attribute__((ext_vector_type(8))) short bf16x8;
typedef __attribute__((ext_vector_type(4))) float f32x4;

#define QSCALE 0.1803368801111f  // 0.125 * log2(e)
#define LG2_10K 0.4152410118f    // log2(10000)/32

__device__ __forceinline__ unsigned short f2bf(float f) {
  union { float f; unsigned u; } v;
  v.f = f;
  unsigned r = v.u + 0x7fffu + ((v.u >> 16) & 1u);
  return (unsigned short)(r >> 16);
}
__device__ __forceinline__ float bf2f(unsigned short u) {
  union { unsigned u; float f; } v;
  v.u = ((unsigned)u) << 16;
  return v.f;
}
__device__ __forceinline__ unsigned fbits(float f) {
  union { float f; unsigned u; } v;
  v.f = f;
  return v.u;
}

__device__ __forceinline__ void glds16(const void* g, void* l) {
  __builtin_amdgcn_global_load_lds(
      (const __attribute__((address_space(1))) unsigned int*)g,
      (__attribute__((address_space(3))) unsigned int*)l, 16, 0, 0);
}

// ---------------- prep: all weight converts (fp32 [K][N] -> bf16 [N][K]) + bias pack ----
__global__ __launch_bounds__(256) void prep(const float* __restrict__ WQ,
                                            const float* __restrict__ WK,
                                            const float* __restrict__ WV,
                                            const float* __restrict__ WO,
                                            const float* __restrict__ W1,
                                            const float* __restrict__ W2,
                                            const float* __restrict__ bQ,
                                            const float* __restrict__ bK,
                                            const float* __restrict__ bV,
                                            unsigned short* __restrict__ WQKVt,
                                            unsigned short* __restrict__ WOt,
                                            unsigned short* __restrict__ W1t,
                                            unsigned short* __restrict__ W2t,
                                            float* __restrict__ bqkv) {
  const int id = blockIdx.x;
  if (id >= 12288) {
    const int i = (id - 12288) * 256 + threadIdx.x;
    if (i < 3072)
      bqkv[i] = (i < 1024) ? bQ[i] : ((i < 2048) ? bK[i - 1024] : bV[i - 2048]);
    return;
  }
  const float* W;
  unsigned short* D;
  int K, N, x, y;
  if (id < 4096) {
    const int m = id >> 10;
    const float* ws4[4] = {WQ, WK, WV, WO};
    unsigned short* ds4[4] = {WQKVt, WQKVt + 1024 * 1024, WQKVt + 2 * 1024 * 1024, WOt};
    W = ws4[m]; D = ds4[m]; K = 1024; N = 1024;
    x = id & 31; y = (id >> 5) & 31;
  } else if (id < 8192) {
    const int j = id - 4096;
    W = W1; D = W1t; K = 1024; N = 4096;
    x = j & 127; y = j >> 7;
  } else {
    const int j = id - 8192;
    W = W2; D = W2t; K = 4096; N = 1024;
    x = j & 31; y = j >> 5;
  }
  __shared__ float t[32][33];
  const int tx = threadIdx.x & 31, ty = threadIdx.x >> 5;
  const int n0 = x * 32, k0 = y * 32;
#pragma unroll
  for (int p = 0; p < 4; ++p)
    t[ty + p * 8][tx] = W[(size_t)(k0 + ty + p * 8) * N + n0 + tx];
  __syncthreads();
#pragma unroll
  for (int p = 0; p < 4; ++p)
    D[(size_t)(n0 + ty + p * 8) * K + k0 + tx] = f2bf(t[tx][ty + p * 8]);
}

// ---------------- RMSNorm: fp32 in, bf16 out; one block per row ----------------
__global__ __launch_bounds__(256) void rmsnorm_kernel(const float* __restrict__ x,
                                                      const float* __restrict__ g,
                                                      unsigned short* __restrict__ out) {
  const int row = blockIdx.x;
  const int t = threadIdx.x;
  const float4 v = ((const float4*)(x + (size_t)row * E_))[t];
  float ss = v.x * v.x + v.y * v.y + v.z * v.z + v.w * v.w;
#pragma unroll
  for (int off = 32; off > 0; off >>= 1) ss += __shfl_down(ss, off);
  __shared__ float sred[4];
  if ((t & 63) == 0) sred[t >> 6] = ss;
  __syncthreads();
  const float tot = sred[0] + sred[1] + sred[2] + sred[3];
  const float rinv = rsqrtf(tot * (1.0f / E_) + 1.1920929e-07f);
  const float4 gv = ((const float4*)g)[t];
  ushort4 o;
  o.x = f2bf(v.x * rinv * gv.x);
  o.y = f2bf(v.y * rinv * gv.y);
  o.z = f2bf(v.z * rinv * gv.z);
  o.w = f2bf(v.w * rinv * gv.w);
  ((ushort4*)(out + (size_t)row * E_))[t] = o;
}

// ======== FF1: hardcoded-constant 8-phase 256x256 BK=64, launch_bounds(512,1) ========
// Schedule identical to gemm256p (R4/R5 refcheck-passed, R6/R8-implied ~52us for FF2 at
// 5.2 TF/CU). Hypothesis under test: HARDCODED dims (literal M/N/K, no runtime division/
// stride math) avoid the VGPR spill that killed the runtime-dim template instances
// (R4/R5/R7: VGPR pinned 128 + 20-30MB scratch). M=8192, N=4096, K=1024, grid 512.
__global__ __launch_bounds__(512, 1) void gemm8pf1(const unsigned short* __restrict__ A,
                                                   const unsigned short* __restrict__ Bt,
                                                   const float* __restrict__ bias,
                                                   unsigned short* __restrict__ C) {
  const int N = 4096, K = 1024;
  __shared__ unsigned short Ls[2][2][256 * 64];
  const int tid = threadIdx.x;
  const int w = tid >> 6;
  const int lane = tid & 63;

  const int id = blockIdx.x;                 // 512 blocks, %8==0 -> bijective swizzle
  const int lid = (id & 7) * 64 + (id >> 3);
  const int bm = (lid >> 4) * 256;           // 32 M-tiles
  const int bn = (lid & 15) * 256;           // 16 N-tiles

  const int wm = (w & 1) * 128, wn = (w >> 1) * 64;

  f32x4 acc[8][4];
#pragma unroll
  for (int i = 0; i < 8; ++i)
#pragma unroll
    for (int j = 0; j < 4; ++j) acc[i][j] = (f32x4){0.f, 0.f, 0.f, 0.f};

  const int srow = lane >> 3;
  const int skb = (lane & 7) ^ srow;
  const unsigned short* Ap[4];
  const unsigned short* Bp[4];
#pragma unroll
  for (int p = 0; p < 4; ++p) {
    const int u = w * 4 + p;
    Ap[p] = A + (size_t)(bm + u * 8 + srow) * K + skb * 8;
    Bp[p] = Bt + (size_t)(bn + u * 8 + srow) * K + skb * 8;
  }

  const int fr = lane & 15;
  const int g = lane >> 4;
  const int sw = fr & 7;

  bf16x8 av[4], bv[4];

#define STG2(tt, sb, p0, p1)                                                  \
  {                                                                           \
    glds16(Ap[p0] + (size_t)(tt) * 64, &Ls[sb][0][(w * 4 + p0) * 512 + lane * 8]); \
    glds16(Bp[p0] + (size_t)(tt) * 64, &Ls[sb][1][(w * 4 + p0) * 512 + lane * 8]); \
    glds16(Ap[p1] + (size_t)(tt) * 64, &Ls[sb][0][(w * 4 + p1) * 512 + lane * 8]); \
    glds16(Bp[p1] + (size_t)(tt) * 64, &Ls[sb][1][(w * 4 + p1) * 512 + lane * 8]); \
  }
#define RDA(cb, kc, h)                                                        \
  _Pragma("unroll") for (int i4 = 0; i4 < 4; ++i4)                            \
      av[i4] = *(const bf16x8*)&Ls[cb][0][(wm + ((h) * 4 + i4) * 16 + fr) * 64 + \
                                          (((kc) * 4 + g) ^ sw) * 8];
#define RDB(cb, kc)                                                           \
  _Pragma("unroll") for (int in = 0; in < 4; ++in)                            \
      bv[in] = *(const bf16x8*)&Ls[cb][1][(wn + in * 16 + fr) * 64 +          \
                                          (((kc) * 4 + g) ^ sw) * 8];
#define LWAIT asm volatile("s_waitcnt lgkmcnt(0)" ::: "memory");
#define VDRAIN asm volatile("s_waitcnt vmcnt(0)" ::: "memory");
#define MFMA16(h)                                                             \
  __builtin_amdgcn_s_setprio(1);                                              \
  _Pragma("unroll") for (int i4 = 0; i4 < 4; ++i4)                            \
  _Pragma("unroll") for (int in = 0; in < 4; ++in)                            \
      acc[(h) * 4 + i4][in] = __builtin_amdgcn_mfma_f32_16x16x32_bf16(        \
          av[i4], bv[in], acc[(h) * 4 + i4][in], 0, 0, 0);                    \
  __builtin_amdgcn_s_setprio(0);

  const int nt = 16;  // K/64
  const int ni = 8;

  STG2(0, 0, 0, 1);
  STG2(0, 0, 2, 3);
  VDRAIN;
  __builtin_amdgcn_s_barrier();

  for (int i = 0; i < ni; ++i) {
    const int t1 = 2 * i + 1;
    const int t2 = 2 * i + 2;

    RDB(0, 0); RDA(0, 0, 0);
    STG2(t1, 1, 0, 1);
    __builtin_amdgcn_s_barrier();
    LWAIT; MFMA16(0);
    __builtin_amdgcn_s_barrier();

    RDA(0, 0, 1);
    STG2(t1, 1, 2, 3);
    __builtin_amdgcn_s_barrier();
    LWAIT; MFMA16(1);
    __builtin_amdgcn_s_barrier();

    RDB(0, 1); RDA(0, 1, 0);
    __builtin_amdgcn_s_barrier();
    LWAIT; MFMA16(0);
    __builtin_amdgcn_s_barrier();

    RDA(0, 1, 1);
    __builtin_amdgcn_s_barrier();
    LWAIT; MFMA16(1);
    VDRAIN;
    __builtin_amdgcn_s_barrier();

    RDB(1, 0); RDA(1, 0, 0);
    if (t2 < nt) STG2(t2, 0, 0, 1);
    __builtin_amdgcn_s_barrier();
    LWAIT; MFMA16(0);
    __builtin_amdgcn_s_barrier();

    RDA(1, 0, 1);
    if (t2 < nt) STG2(t2, 0, 2, 3);
    __builtin_amdgcn_s_barrier();
    LWAIT; MFMA16(1);
    __builtin_amdgcn_s_barrier();

    RDB(1, 1); RDA(1, 1, 0);
    __builtin_amdgcn_s_barrier();
    LWAIT; MFMA16(0);
    __builtin_amdgcn_s_barrier();

    RDA(1, 1, 1);
    __builtin_amdgcn_s_barrier();
    LWAIT; MFMA16(1);
    VDRAIN;
    __builtin_amdgcn_s_barrier();
  }

  // bias + relu + bf16 store
#pragma unroll
  for (int im = 0; im < 8; ++im) {
    const int row0 = bm + wm + im * 16 + g * 4;
#pragma unroll
    for (int in = 0; in < 4; ++in) {
      const int col = bn + wn + in * 16 + fr;
      const float bvv = bias[col];
#pragma unroll
      for (int r = 0; r < 4; ++r) {
        float v = acc[im][in][r] + bvv;
        v = fmaxf(v, 0.0f);
        C[(size_t)(row0 + r) * N + col] = f2bf(v);
      }
    }
  }
#undef STG2
#undef RDA
#undef RDB
#undef LWAIT
#undef VDRAIN
#undef MFMA16
}

// ======== FF2: hardcoded 8-phase split-K=2 (R6-proven, ~52us implied) ========
__global__ __launch_bounds__(512, 1) void gemm256p(const unsigned short* __restrict__ A,
                                                   const unsigned short* __restrict__ Bt,
                                                   unsigned short* __restrict__ Pp) {
  const int M = 8192, N = 1024, K = 4096, KH = 2048;
  __shared__ unsigned short Ls[2][2][256 * 64];
  const int tid = threadIdx.x;
  const int w = tid >> 6;
  const int lane = tid & 63;

  int id = blockIdx.x;
  const int kh = id >> 7;
  id &= 127;
  const int lid = (id & 7) * 16 + (id >> 3);
  const int bm = (lid >> 2) * 256;
  const int bn = (lid & 3) * 256;

  const unsigned short* Ab = A + (size_t)kh * KH;
  const unsigned short* Bb = Bt + (size_t)kh * KH;

  const int wm = (w & 1) * 128, wn = (w >> 1) * 64;

  f32x4 acc[8][4];
#pragma unroll
  for (int i = 0; i < 8; ++i)
#pragma unroll
    for (int j = 0; j < 4; ++j) acc[i][j] = (f32x4){0.f, 0.f, 0.f, 0.f};

  const int srow = lane >> 3;
  const int skb = (lane & 7) ^ srow;
  const unsigned short* Ap[4];
  const unsigned short* Bp[4];
#pragma unroll
  for (int p = 0; p < 4; ++p) {
    const int u = w * 4 + p;
    Ap[p] = Ab + (size_t)(bm + u * 8 + srow) * K + skb * 8;
    Bp[p] = Bb + (size_t)(bn + u * 8 + srow) * K + skb * 8;
  }

  const int fr = lane & 15;
  const int g = lane >> 4;
  const int sw = fr & 7;

  bf16x8 av[4], bv[4];

#define STG2(tt, sb, p0, p1)                                                  \
  {                                                                           \
    glds16(Ap[p0] + (size_t)(tt) * 64, &Ls[sb][0][(w * 4 + p0) * 512 + lane * 8]); \
    glds16(Bp[p0] + (size_t)(tt) * 64, &Ls[sb][1][(w * 4 + p0) * 512 + lane * 8]); \
    glds16(Ap[p1] + (size_t)(tt) * 64, &Ls[sb][0][(w * 4 + p1) * 512 + lane * 8]); \
    glds16(Bp[p1] + (size_t)(tt) * 64, &Ls[sb][1][(w * 4 + p1) * 512 + lane * 8]); \
  }
#define RDA(cb, kc, h)                                                        \
  _Pragma("unroll") for (int i4 = 0; i4 < 4; ++i4)                            \
      av[i4] = *(const bf16x8*)&Ls[cb][0][(wm + ((h) * 4 + i4) * 16 + fr) * 64 + \
                                          (((kc) * 4 + g) ^ sw) * 8];
#define RDB(cb, kc)                                                           \
  _Pragma("unroll") for (int in = 0; in < 4; ++in)                            \
      bv[in] = *(const bf16x8*)&Ls[cb][1][(wn + in * 16 + fr) * 64 +          \
                                          (((kc) * 4 + g) ^ sw) * 8];
#define LWAIT asm volatile("s_waitcnt lgkmcnt(0)" ::: "memory");
#define VDRAIN asm volatile("s_waitcnt vmcnt(0)" ::: "memory");
#define MFMA16(h)                                                             \
  __builtin_amdgcn_s_setprio(1);                                              \
  _Pragma("unroll") for (int i4 = 0; i4 < 4; ++i4)                            \
  _Pragma("unroll") for (int in = 0; in < 4; ++in)                            \
      acc[(h) * 4 + i4][in] = __builtin_amdgcn_mfma_f32_16x16x32_bf16(        \
          av[i4], bv[in], acc[(h) * 4 + i4][in], 0, 0, 0);                    \
  __builtin_amdgcn_s_setprio(0);

  const int nt = KH >> 6;   // 32
  const int ni = nt >> 1;   // 16

  STG2(0, 0, 0, 1);
  STG2(0, 0, 2, 3);
  VDRAIN;
  __builtin_amdgcn_s_barrier();

  for (int i = 0; i < ni; ++i) {
    const int t1 = 2 * i + 1;
    const int t2 = 2 * i + 2;

    RDB(0, 0); RDA(0, 0, 0);
    STG2(t1, 1, 0, 1);
    __builtin_amdgcn_s_barrier();
    LWAIT; MFMA16(0);
    __builtin_amdgcn_s_barrier();

    RDA(0, 0, 1);
    STG2(t1, 1, 2, 3);
    __builtin_amdgcn_s_barrier();
    LWAIT; MFMA16(1);
    __builtin_amdgcn_s_barrier();

    RDB(0, 1); RDA(0, 1, 0);
    __builtin_amdgcn_s_barrier();
    LWAIT; MFMA16(0);
    __builtin_amdgcn_s_barrier();

    RDA(0, 1, 1);
    __builtin_amdgcn_s_barrier();
    LWAIT; MFMA16(1);
    VDRAIN;
    __builtin_amdgcn_s_barrier();

    RDB(1, 0); RDA(1, 0, 0);
    if (t2 < nt) STG2(t2, 0, 0, 1);
    __builtin_amdgcn_s_barrier();
    LWAIT; MFMA16(0);
    __builtin_amdgcn_s_barrier();

    RDA(1, 0, 1);
    if (t2 < nt) STG2(t2, 0, 2, 3);
    __builtin_amdgcn_s_barrier();
    LWAIT; MFMA16(1);
    __builtin_amdgcn_s_barrier();

    RDB(1, 1); RDA(1, 1, 0);
    __builtin_amdgcn_s_barrier();
    LWAIT; MFMA16(0);
    __builtin_amdgcn_s_barrier();

    RDA(1, 1, 1);
    __builtin_amdgcn_s_barrier();
    LWAIT; MFMA16(1);
    VDRAIN;
    __builtin_amdgcn_s_barrier();
  }

  unsigned short* P = Pp + (size_t)kh * ((size_t)M * N);
#pragma unroll
  for (int im = 0; im < 8; ++im) {
    const int row0 = bm + wm + im * 16 + g * 4;
#pragma unroll
    for (int in = 0; in < 4; ++in) {
      const int col = bn + wn + in * 16 + fr;
#pragma unroll
      for (int r = 0; r < 4; ++r)
        P[(size_t)(row0 + r) * N + col] = f2bf(acc[im][in][r]);
    }
  }
#undef STG2
#undef RDA
#undef RDB
#undef LWAIT
#undef VDRAIN
#undef MFMA16
}

// ---------------- FF2 combine: out = x1 + b2 + P0 + P1 ----------------
__global__ __launch_bounds__(256) void ff2_reduce(const unsigned short* __restrict__ Pp,
                                                  const float* __restrict__ x1,
                                                  const float* __restrict__ b2,
                                                  float* __restrict__ out) {
  const int i = blockIdx.x * 256 + threadIdx.x;
  const size_t off = (size_t)i * 4;
  const ushort4 p0 = *(const ushort4*)(Pp + off);
  const ushort4 p1 = *(const ushort4*)(Pp + (8u << 20) + off);
  const float4 xv = *(const float4*)(x1 + off);
  const float4 bv = *(const float4*)(b2 + (off & 1023));
  float4 o;
  o.x = xv.x + bv.x + bf2f(p0.x) + bf2f(p1.x);
  o.y = xv.y + bv.y + bf2f(p0.y) + bf2f(p1.y);
  o.z = xv.z + bv.z + bf2f(p0.z) + bf2f(p1.z);
  o.w = xv.w + bv.w + bf2f(p0.w) + bf2f(p1.w);
  *(float4*)(out + off) = o;
}

// ---------------- bf16 MFMA GEMM 128x128, BK=64, XCD-swizzled 1D grid ------------
// R1-proven ~800 TF. Used for O-proj (res=x, fp32 out).
template <int OUT_BF16, int RELU, int RES>
__global__ __launch_bounds__(256) void gemm_bf16(const unsigned short* __restrict__ A,
                                                 const unsigned short* __restrict__ Bt,
                                                 const float* __restrict__ bias,
                                                 const float* __restrict__ res,
                                                 void* __restrict__ C,
                                                 int M, int N, int K) {
  __shared__ unsigned short As[128 * 64];
  __shared__ unsigned short Bs[128 * 64];
  const int tid = threadIdx.x;
  const int w = tid >> 6;
  const int lane = tid & 63;

  const int nb = gridDim.x;
  const int id = blockIdx.x;
  const int lid = (id & 7) * (nb >> 3) + (id >> 3);
  const int per = (M >> 7) * 8;
  const int grp = lid / per;
  const int rem = lid - grp * per;
  const int bn = (grp * 8 + (rem & 7)) * 128;
  const int bm = (rem >> 3) * 128;

  const int wm = (w & 1) * 64, wn = (w >> 1) * 64;

  f32x4 acc[4][4];
#pragma unroll
  for (int i = 0; i < 4; ++i)
#pragma unroll
    for (int j = 0; j < 4; ++j) acc[i][j] = (f32x4){0.f, 0.f, 0.f, 0.f};

  const int srow = lane >> 3;
  const int skb = (lane & 7) ^ srow;  // swizzled source 16B-slot
  const unsigned short* Ap[4];
  const unsigned short* Bp[4];
  unsigned short* AsD[4];
  unsigned short* BsD[4];
#pragma unroll
  for (int p = 0; p < 4; ++p) {
    const int u = w * 4 + p;
    Ap[p] = A + (size_t)(bm + u * 8 + srow) * K + skb * 8;
    Bp[p] = Bt + (size_t)(bn + u * 8 + srow) * K + skb * 8;
    AsD[p] = &As[u * 512 + lane * 8];
    BsD[p] = &Bs[u * 512 + lane * 8];
  }

  const int fr = lane & 15;
  const int g = lane >> 4;
  const int sw = fr & 7;

  for (int k0 = 0; k0 < K; k0 += 64) {
    __syncthreads();
#pragma unroll
    for (int p = 0; p < 4; ++p) glds16(Ap[p] + k0, AsD[p]);
#pragma unroll
    for (int p = 0; p < 4; ++p) glds16(Bp[p] + k0, BsD[p]);
    __syncthreads();
    bf16x8 a[4][2], b[4][2];
#pragma unroll
    for (int im = 0; im < 4; ++im)
#pragma unroll
      for (int kc = 0; kc < 2; ++kc)
        a[im][kc] = *(const bf16x8*)&As[(wm + im * 16 + fr) * 64 + ((kc * 4 + g) ^ sw) * 8];
#pragma unroll
    for (int in = 0; in < 4; ++in)
#pragma unroll
      for (int kc = 0; kc < 2; ++kc)
        b[in][kc] = *(const bf16x8*)&Bs[(wn + in * 16 + fr) * 64 + ((kc * 4 + g) ^ sw) * 8];
#pragma unroll
    for (int im = 0; im < 4; ++im)
#pragma unroll
      for (int in = 0; in < 4; ++in) {
        acc[im][in] = __builtin_amdgcn_mfma_f32_16x16x32_bf16(a[im][0], b[in][0], acc[im][in], 0, 0, 0);
        acc[im][in] = __builtin_amdgcn_mfma_f32_16x16x32_bf16(a[im][1], b[in][1], acc[im][in], 0, 0, 0);
      }
  }

#pragma unroll
  for (int im = 0; im < 4; ++im) {
    const int row0 = bm + wm + im * 16 + (lane >> 4) * 4;
#pragma unroll
    for (int in = 0; in < 4; ++in) {
      const int col = bn + wn + in * 16 + fr;
      const float bv = bias[col];
#pragma unroll
      for (int r = 0; r < 4; ++r) {
        float v = acc[im][in][r] + bv;
        if (RES) v += res[(size_t)(row0 + r) * N + col];
        if (RELU) v = fmaxf(v, 0.0f);
        if (OUT_BF16)
          ((unsigned short*)C)[(size_t)(row0 + r) * N + col] = f2bf(v);
        else
          ((float*)C)[(size_t)(row0 + r) * N + col] = v;
      }
    }
  }
}

// ---------------- QKV GEMM (BK=64) with fused RoPE (Q,K) + transposed V store ----------
__global__ __launch_bounds__(256) void gemm_qkv(const unsigned short* __restrict__ A,
                                                const unsigned short* __restrict__ Bt,
                                                const float* __restrict__ bias,
                                                unsigned short* __restrict__ QKV,
                                                unsigned short* __restrict__ Vt,
                                                int M, int K) {
  __shared__ unsigned short As[128 * 64];
  __shared__ unsigned short Bs[128 * 64];
  const int tid = threadIdx.x;
  const int w = tid >> 6;
  const int lane = tid & 63;

  const int nb = gridDim.x;
  const int id = blockIdx.x;
  const int lid = (id & 7) * (nb >> 3) + (id >> 3);
  const int per = (M >> 7) * 8;
  const int grp = lid / per;
  const int rem = lid - grp * per;
  const int bn = (grp * 8 + (rem & 7)) * 128;
  const int bm = (rem >> 3) * 128;

  const int wm = (w & 1) * 64, wn = (w >> 1) * 64;

  f32x4 acc[4][4];
#pragma unroll
  for (int i = 0; i < 4; ++i)
#pragma unroll
    for (int j = 0; j < 4; ++j) acc[i][j] = (f32x4){0.f, 0.f, 0.f, 0.f};

  const int srow = lane >> 3;
  const int skb = (lane & 7) ^ srow;
  const unsigned short* Ap[4];
  const unsigned short* Bp[4];
  unsigned short* AsD[4];
  unsigned short* BsD[4];
#pragma unroll
  for (int p = 0; p < 4; ++p) {
    const int u = w * 4 + p;
    Ap[p] = A + (size_t)(bm + u * 8 + srow) * K + skb * 8;
    Bp[p] = Bt + (size_t)(bn + u * 8 + srow) * K + skb * 8;
    AsD[p] = &As[u * 512 + lane * 8];
    BsD[p] = &Bs[u * 512 + lane * 8];
  }

  const int fr = lane & 15;
  const int g = lane >> 4;
  const int sw = fr & 7;

  for (int k0 = 0; k0 < K; k0 += 64) {
    __syncthreads();
#pragma unroll
    for (int p = 0; p < 4; ++p) glds16(Ap[p] + k0, AsD[p]);
#pragma unroll
    for (int p = 0; p < 4; ++p) glds16(Bp[p] + k0, BsD[p]);
    __syncthreads();
    bf16x8 a[4][2], b[4][2];
#pragma unroll
    for (int im = 0; im < 4; ++im)
#pragma unroll
      for (int kc = 0; kc < 2; ++kc)
        a[im][kc] = *(const bf16x8*)&As[(wm + im * 16 + fr) * 64 + ((kc * 4 + g) ^ sw) * 8];
#pragma unroll
    for (int in = 0; in < 4; ++in)
#pragma unroll
      for (int kc = 0; kc < 2; ++kc)
        b[in][kc] = *(const bf16x8*)&Bs[(wn + in * 16 + fr) * 64 + ((kc * 4 + g) ^ sw) * 8];
#pragma unroll
    for (int im = 0; im < 4; ++im)
#pragma unroll
      for (int in = 0; in < 4; ++in) {
        acc[im][in] = __builtin_amdgcn_mfma_f32_16x16x32_bf16(a[im][0], b[in][0], acc[im][in], 0, 0, 0);
        acc[im][in] = __builtin_amdgcn_mfma_f32_16x16x32_bf16(a[im][1], b[in][1], acc[im][in], 0, 0, 0);
      }
  }

  const int cbase = bn + wn;
  const int seg = cbase >> 6;
  const int typ = seg >> 4;
  const int hh = seg & 15;
  const int bidx = bm >> 10;
  float bv[4];
#pragma unroll
  for (int in = 0; in < 4; ++in) bv[in] = bias[cbase + in * 16 + fr];

  if (typ == 2) {
#pragma unroll
    for (int im = 0; im < 4; ++im) {
      const int s0 = (bm & 1023) + wm + im * 16 + (lane >> 4) * 4;
#pragma unroll
      for (int in = 0; in < 4; ++in) {
        const int d = in * 16 + fr;
        ushort4 o4;
        o4.x = f2bf(acc[im][in][0] + bv[in]);
        o4.y = f2bf(acc[im][in][1] + bv[in]);
        o4.z = f2bf(acc[im][in][2] + bv[in]);
        o4.w = f2bf(acc[im][in][3] + bv[in]);
        *(ushort4*)&Vt[(size_t)((bidx * 16 + hh) * 64 + d) * S_ + s0] = o4;
      }
    }
  } else {
    const float qs = (typ == 0) ? QSCALE : 1.0f;
    const float i0 = exp2f(-LG2_10K * (float)fr);
    const float i1 = exp2f(-LG2_10K * (float)(fr + 16));
#pragma unroll
    for (int im = 0; im < 4; ++im) {
      const int row0 = bm + wm + im * 16 + (lane >> 4) * 4;
#pragma unroll
      for (int r = 0; r < 4; ++r) {
        const int row = row0 + r;
        const float s = (float)(row & 1023);
        float sn0, cs0, sn1, cs1;
        __sincosf(s * i0, &sn0, &cs0);
        __sincosf(s * i1, &sn1, &cs1);
        const float x0 = acc[im][0][r] + bv[0];
        const float x1 = acc[im][1][r] + bv[1];
        const float x2 = acc[im][2][r] + bv[2];
        const float x3 = acc[im][3][r] + bv[3];
        unsigned short* cp = QKV + (size_t)row * 3072 + cbase;
        cp[fr]      = f2bf((x0 * cs0 - x2 * sn0) * qs);
        cp[16 + fr] = f2bf((x1 * cs1 - x3 * sn1) * qs);
        cp[32 + fr] = f2bf((x2 * cs0 + x0 * sn0) * qs);
        cp[48 + fr] = f2bf((x3 * cs1 + x1 * sn1) * qs);
      }
    }
  }
}

// ---------------- MFMA flash attention v4: S^T form + double-buffered K/V staging -------
__global__ __launch_bounds__(256) void attn_v4(const unsigned short* __restrict__ QKV,
                                               const unsigned short* __restrict__ Vt,
                                               unsigned short* __restrict__ Og) {
  __shared__ unsigned short Kf[2][8 * 512];
  __shared__ unsigned short Vf[2][8 * 512];
  __shared__ unsigned short Ps[4][32 * 72];
  const int tid = threadIdx.x;
  const int w = tid >> 6, lane = tid & 63;
  const int qt = blockIdx.x, bh = blockIdx.y;
  const int b = bh >> 4, h = bh & 15;
  const int fr = lane & 15, g = lane >> 4, fk = g * 8;
  const int q0w = qt * 128 + w * 32;

  bf16x8 qB[2][2];
#pragma unroll
  for (int nt = 0; nt < 2; ++nt)
#pragma unroll
    for (int c = 0; c < 2; ++c)
      qB[nt][c] = *(const bf16x8*)&QKV[(size_t)(b * S_ + q0w + nt * 16 + fr) * 3072 +
                                       h * 64 + c * 32 + fk];

  f32x4 o[4][2];
#pragma unroll
  for (int mt = 0; mt < 4; ++mt)
#pragma unroll
    for (int nt = 0; nt < 2; ++nt) o[mt][nt] = (f32x4){0.f, 0.f, 0.f, 0.f};
  float l[2] = {0.0f, 0.0f};

#define STAGE(kt, bufi)                                                                   \
  {                                                                                       \
    _Pragma("unroll") for (int p = 0; p < 4; ++p) {                                       \
      const int u = w * 4 + p;                                                            \
      if (u < 8) {                                                                        \
        const int mt = u >> 1, c = u & 1;                                                 \
        glds16(QKV + (size_t)(b * S_ + (kt) * 64 + mt * 16 + fr) * 3072 + 1024 + h * 64 + \
                   c * 32 + fk,                                                           \
               &Kf[bufi][u * 512]);                                                       \
      } else {                                                                            \
        const int v2 = u - 8, mt = v2 >> 1, c = v2 & 1;                                   \
        glds16(Vt + (size_t)(bh * 64 + mt * 16 + fr) * S_ + (kt) * 64 + c * 32 + fk,      \
               &Vf[bufi][v2 * 512]);                                                      \
      }                                                                                   \
    }                                                                                     \
  }

  STAGE(0, 0);

  for (int kt = 0; kt < 16; ++kt) {
    __syncthreads();
    if (kt < 15) STAGE(kt + 1, (kt + 1) & 1);
    const unsigned short* Kc = Kf[kt & 1];
    const unsigned short* Vc = Vf[kt & 1];

    f32x4 s[4][2];
#pragma unroll
    for (int mt = 0; mt < 4; ++mt) {
      const bf16x8 k0 = *(const bf16x8*)&Kc[(mt * 2 + 0) * 512 + lane * 8];
      const bf16x8 k1 = *(const bf16x8*)&Kc[(mt * 2 + 1) * 512 + lane * 8];
#pragma unroll
      for (int nt = 0; nt < 2; ++nt) {
        f32x4 a = (f32x4){0.f, 0.f, 0.f, 0.f};
        a = __builtin_amdgcn_mfma_f32_16x16x32_bf16(k0, qB[nt][0], a, 0, 0, 0);
        a = __builtin_amdgcn_mfma_f32_16x16x32_bf16(k1, qB[nt][1], a, 0, 0, 0);
        s[mt][nt] = a;
      }
    }

#pragma unroll
    for (int nt = 0; nt < 2; ++nt) {
      float rs = 0.0f;
#pragma unroll
      for (int mt = 0; mt < 4; ++mt)
#pragma unroll
        for (int r = 0; r < 4; ++r) {
          const float p = exp2f(s[mt][nt][r]);
          s[mt][nt][r] = p;
          rs += p;
        }
      rs += __shfl_xor(rs, 16);
      rs += __shfl_xor(rs, 32);
      l[nt] += rs;
    }

#pragma unroll
    for (int nt = 0; nt < 2; ++nt)
#pragma unroll
      for (int mt = 0; mt < 4; ++mt) {
        uint2 pk;
        pk.x = __builtin_amdgcn_perm(fbits(s[mt][nt][1]), fbits(s[mt][nt][0]), 0x07060302u);
        pk.y = __builtin_amdgcn_perm(fbits(s[mt][nt][3]), fbits(s[mt][nt][2]), 0x07060302u);
        *(uint2*)&Ps[w][(nt * 16 + fr) * 72 + mt * 16 + g * 4] = pk;
      }

    bf16x8 pB[2][2];
#pragma unroll
    for (int nt = 0; nt < 2; ++nt)
#pragma unroll
      for (int c = 0; c < 2; ++c)
        pB[nt][c] = *(const bf16x8*)&Ps[w][(nt * 16 + fr) * 72 + c * 32 + fk];
#pragma unroll
    for (int mt = 0; mt < 4; ++mt) {
      const bf16x8 v0 = *(const bf16x8*)&Vc[(mt * 2 + 0) * 512 + lane * 8];
      const bf16x8 v1 = *(const bf16x8*)&Vc[(mt * 2 + 1) * 512 + lane * 8];
#pragma unroll
      for (int nt = 0; nt < 2; ++nt) {
        o[mt][nt] = __builtin_amdgcn_mfma_f32_16x16x32_bf16(v0, pB[nt][0], o[mt][nt], 0, 0, 0);
        o[mt][nt] = __builtin_amdgcn_mfma_f32_16x16x32_bf16(v1, pB[nt][1], o[mt][nt], 0, 0, 0);
      }
    }
  }

  const float linv0 = 1.0f / l[0], linv1 = 1.0f / l[1];
#pragma unroll
  for (int nt = 0; nt < 2; ++nt) {
    const float li = nt ? linv1 : linv0;
#pragma unroll
    for (int mt = 0; mt < 4; ++mt) {
      uint2 pk;
      pk.x = __builtin_amdgcn_perm(fbits(o[mt][nt][1] * li), fbits(o[mt][nt][0] * li), 0x07060302u);
      pk.y = __builtin_amdgcn_perm(fbits(o[mt][nt][3] * li), fbits(o[mt][nt][2] * li), 0x07060302u);
      *(uint2*)&Ps[w][(nt * 16 + fr) * 72 + mt * 16 + g * 4] = pk;
    }
  }
  const int qr = lane >> 1, hf = lane & 1;
#pragma unroll
  for (int c = 0; c < 2; ++c) {
    const bf16x8 vv = *(const bf16x8*)&Ps[w][qr * 72 + hf * 16 + c * 32];
    *(bf16x8*)&Og[(size_t)(b * S_ + q0w + qr) * E_ + h * 64 + hf * 16 + c * 32] = vv;
  }
}

extern "C" void kernel_launch(void* const* d_in, const int* in_sizes, int n_in,
                              void* d_out, int out_size, void* d_ws, size_t ws_size,
                              hipStream_t stream) {
  const float* x  = (const float*)d_in[0];
  const float* WQ = (const float*)d_in[1];
  const float* bQ = (const float*)d_in[2];
  const float* WK = (const float*)d_in[3];
  const float* bK = (const float*)d_in[4];
  const float* WV = (const float*)d_in[5];
  const float* bV = (const float*)d_in[6];
  const float* WO = (const float*)d_in[7];
  const float* bO = (const float*)d_in[8];
  const float* W1 = (const float*)d_in[9];
  const float* b1 = (const float*)d_in[10];
  const float* W2 = (const float*)d_in[11];
  const float* b2 = (const float*)d_in[12];
  const float* g1 = (const float*)d_in[13];
  const float* g2 = (const float*)d_in[14];
  float* out = (float*)d_out;

  char* ws = (char*)d_ws;
  const size_t MB = 1024 * 1024;
  unsigned short* h1   = (unsigned short*)(ws + 0 * MB);
  unsigned short* QKV  = (unsigned short*)(ws + 16 * MB);   // [8192,3072]
  unsigned short* Vt   = (unsigned short*)(ws + 64 * MB);   // [128*64,1024]
  unsigned short* Ob   = (unsigned short*)(ws + 80 * MB);
  float*          x1   = (float*)(ws + 96 * MB);
  unsigned short* h2   = (unsigned short*)(ws + 128 * MB);
  unsigned short* mid  = (unsigned short*)(ws + 16 * MB);   // reuses QKV+Vt region
  unsigned short* WQKVt= (unsigned short*)(ws + 144 * MB);
  unsigned short* WOt  = (unsigned short*)(ws + 150 * MB);
  unsigned short* W1t  = (unsigned short*)(ws + 152 * MB);
  unsigned short* W2t  = (unsigned short*)(ws + 160 * MB);
  float*          bqkv = (float*)(ws + 168 * MB);
  unsigned short* Pp   = (unsigned short*)(ws + 176 * MB);  // [2][8192,1024] bf16 partials

  const int M = B_ * S_;

  prep<<<12300, 256, 0, stream>>>(WQ, WK, WV, WO, W1, W2, bQ, bK, bV,
                                  WQKVt, WOt, W1t, W2t, bqkv);

  rmsnorm_kernel<<<M, 256, 0, stream>>>(x, g1, h1);

  gemm_qkv<<<24 * 64, 256, 0, stream>>>(h1, WQKVt, bqkv, QKV, Vt, M, E_);

  attn_v4<<<dim3(8, B_ * H_), 256, 0, stream>>>(QKV, Vt, Ob);

  // O-proj: 128x128 tile, res-add x, fp32 out
  gemm_bf16<0, 0, 1><<<64 * 8, 256, 0, stream>>>(Ob, WOt, bO, x, x1, M, E_, E_);

  rmsnorm_kernel<<<M, 256, 0, stream>>>(x1, g2, h2);

  // FF1 EXPERIMENT: hardcoded-constant 8-phase (512,1). Success => ~55us; fail => revert.
  gemm8pf1<<<512, 512, 0, stream>>>(h2, W1t, b1, mid);

  // FF2: hardcoded 8-phase split-K=2 (R6-proven ~52us)
  gemm256p<<<256, 512, 0, stream>>>(mid, W2t, Pp);

  ff2_reduce<<<8192, 256, 0, stream>>>(Pp, x1, b2, out);
}

// Round 10
// 466.479 us; speedup vs baseline: 1.0929x; 1.0174x over previous
//
#include <hip/hip_runtime.h>
#include <math.h>

#define B_ 8
#define S_ 1024
#define E_ 1024
#define H_ 16
#define FF_ 4096

typedef __attribute__((ext_vector_type(8))) short bf16x8;
typedef __attribute__((ext_vector_type(4))) float f32x4;

#define QSCALE 0.1803368801111f  // 0.125 * log2(e)
#define LG2_10K 0.4152410118f    // log2(10000)/32

__device__ __forceinline__ unsigned short f2bf(float f) {
  union { float f; unsigned u; } v;
  v.f = f;
  unsigned r = v.u + 0x7fffu + ((v.u >> 16) & 1u);
  return (unsigned short)(r >> 16);
}
__device__ __forceinline__ float bf2f(unsigned short u) {
  union { unsigned u; float f; } v;
  v.u = ((unsigned)u) << 16;
  return v.f;
}
__device__ __forceinline__ unsigned fbits(float f) {
  union { float f; unsigned u; } v;
  v.f = f;
  return v.u;
}

__device__ __forceinline__ void glds16(const void* g, void* l) {
  __builtin_amdgcn_global_load_lds(
      (const __attribute__((address_space(1))) unsigned int*)g,
      (__attribute__((address_space(3))) unsigned int*)l, 16, 0, 0);
}

// ---------------- prep: all weight converts (fp32 [K][N] -> bf16 [N][K]) + bias pack ----
__global__ __launch_bounds__(256) void prep(const float* __restrict__ WQ,
                                            const float* __restrict__ WK,
                                            const float* __restrict__ WV,
                                            const float* __restrict__ WO,
                                            const float* __restrict__ W1,
                                            const float* __restrict__ W2,
                                            const float* __restrict__ bQ,
                                            const float* __restrict__ bK,
                                            const float* __restrict__ bV,
                                            unsigned short* __restrict__ WQKVt,
                                            unsigned short* __restrict__ WOt,
                                            unsigned short* __restrict__ W1t,
                                            unsigned short* __restrict__ W2t,
                                            float* __restrict__ bqkv) {
  const int id = blockIdx.x;
  if (id >= 12288) {
    const int i = (id - 12288) * 256 + threadIdx.x;
    if (i < 3072)
      bqkv[i] = (i < 1024) ? bQ[i] : ((i < 2048) ? bK[i - 1024] : bV[i - 2048]);
    return;
  }
  const float* W;
  unsigned short* D;
  int K, N, x, y;
  if (id < 4096) {
    const int m = id >> 10;
    const float* ws4[4] = {WQ, WK, WV, WO};
    unsigned short* ds4[4] = {WQKVt, WQKVt + 1024 * 1024, WQKVt + 2 * 1024 * 1024, WOt};
    W = ws4[m]; D = ds4[m]; K = 1024; N = 1024;
    x = id & 31; y = (id >> 5) & 31;
  } else if (id < 8192) {
    const int j = id - 4096;
    W = W1; D = W1t; K = 1024; N = 4096;
    x = j & 127; y = j >> 7;
  } else {
    const int j = id - 8192;
    W = W2; D = W2t; K = 4096; N = 1024;
    x = j & 31; y = j >> 5;
  }
  __shared__ float t[32][33];
  const int tx = threadIdx.x & 31, ty = threadIdx.x >> 5;
  const int n0 = x * 32, k0 = y * 32;
#pragma unroll
  for (int p = 0; p < 4; ++p)
    t[ty + p * 8][tx] = W[(size_t)(k0 + ty + p * 8) * N + n0 + tx];
  __syncthreads();
#pragma unroll
  for (int p = 0; p < 4; ++p)
    D[(size_t)(n0 + ty + p * 8) * K + k0 + tx] = f2bf(t[tx][ty + p * 8]);
}

// ---------------- RMSNorm: fp32 in, bf16 out; one block per row ----------------
__global__ __launch_bounds__(256) void rmsnorm_kernel(const float* __restrict__ x,
                                                      const float* __restrict__ g,
                                                      unsigned short* __restrict__ out) {
  const int row = blockIdx.x;
  const int t = threadIdx.x;
  const float4 v = ((const float4*)(x + (size_t)row * E_))[t];
  float ss = v.x * v.x + v.y * v.y + v.z * v.z + v.w * v.w;
#pragma unroll
  for (int off = 32; off > 0; off >>= 1) ss += __shfl_down(ss, off);
  __shared__ float sred[4];
  if ((t & 63) == 0) sred[t >> 6] = ss;
  __syncthreads();
  const float tot = sred[0] + sred[1] + sred[2] + sred[3];
  const float rinv = rsqrtf(tot * (1.0f / E_) + 1.1920929e-07f);
  const float4 gv = ((const float4*)g)[t];
  ushort4 o;
  o.x = f2bf(v.x * rinv * gv.x);
  o.y = f2bf(v.y * rinv * gv.y);
  o.z = f2bf(v.z * rinv * gv.z);
  o.w = f2bf(v.w * rinv * gv.w);
  ((ushort4*)(out + (size_t)row * E_))[t] = o;
}

// ======== shared 8-phase core macros (hardcoded-dim kernels only; runtime-dim
// instances spill — R4/R5/R7 lesson) ========
#define STG2(tt, sb, p0, p1)                                                  \
  {                                                                           \
    glds16(Ap[p0] + (size_t)(tt) * 64, &Ls[sb][0][(w * 4 + p0) * 512 + lane * 8]); \
    glds16(Bp[p0] + (size_t)(tt) * 64, &Ls[sb][1][(w * 4 + p0) * 512 + lane * 8]); \
    glds16(Ap[p1] + (size_t)(tt) * 64, &Ls[sb][0][(w * 4 + p1) * 512 + lane * 8]); \
    glds16(Bp[p1] + (size_t)(tt) * 64, &Ls[sb][1][(w * 4 + p1) * 512 + lane * 8]); \
  }
#define RDA(cb, kc, h)                                                        \
  _Pragma("unroll") for (int i4 = 0; i4 < 4; ++i4)                            \
      av[i4] = *(const bf16x8*)&Ls[cb][0][(wm + ((h) * 4 + i4) * 16 + fr) * 64 + \
                                          (((kc) * 4 + g) ^ sw) * 8];
#define RDB(cb, kc)                                                           \
  _Pragma("unroll") for (int in = 0; in < 4; ++in)                            \
      bv[in] = *(const bf16x8*)&Ls[cb][1][(wn + in * 16 + fr) * 64 +          \
                                          (((kc) * 4 + g) ^ sw) * 8];
#define LWAIT asm volatile("s_waitcnt lgkmcnt(0)" ::: "memory");
#define VDRAIN asm volatile("s_waitcnt vmcnt(0)" ::: "memory");
#define MFMA16(h)                                                             \
  __builtin_amdgcn_s_setprio(1);                                              \
  _Pragma("unroll") for (int i4 = 0; i4 < 4; ++i4)                            \
  _Pragma("unroll") for (int in = 0; in < 4; ++in)                            \
      acc[(h) * 4 + i4][in] = __builtin_amdgcn_mfma_f32_16x16x32_bf16(        \
          av[i4], bv[in], acc[(h) * 4 + i4][in], 0, 0, 0);                    \
  __builtin_amdgcn_s_setprio(0);
// one iteration = 2 K-tiles (buf0 phases 0-3, buf1 phases 4-7)
#define EIGHT_PHASE_ITER(t1, t2, nt)                                          \
  {                                                                           \
    RDB(0, 0); RDA(0, 0, 0);                                                  \
    STG2(t1, 1, 0, 1);                                                        \
    __builtin_amdgcn_s_barrier();                                             \
    LWAIT; MFMA16(0);                                                         \
    __builtin_amdgcn_s_barrier();                                             \
    RDA(0, 0, 1);                                                             \
    STG2(t1, 1, 2, 3);                                                        \
    __builtin_amdgcn_s_barrier();                                             \
    LWAIT; MFMA16(1);                                                         \
    __builtin_amdgcn_s_barrier();                                             \
    RDB(0, 1); RDA(0, 1, 0);                                                  \
    __builtin_amdgcn_s_barrier();                                             \
    LWAIT; MFMA16(0);                                                         \
    __builtin_amdgcn_s_barrier();                                             \
    RDA(0, 1, 1);                                                             \
    __builtin_amdgcn_s_barrier();                                             \
    LWAIT; MFMA16(1);                                                         \
    VDRAIN;                                                                   \
    __builtin_amdgcn_s_barrier();                                             \
    RDB(1, 0); RDA(1, 0, 0);                                                  \
    if (t2 < nt) STG2(t2, 0, 0, 1);                                           \
    __builtin_amdgcn_s_barrier();                                             \
    LWAIT; MFMA16(0);                                                         \
    __builtin_amdgcn_s_barrier();                                             \
    RDA(1, 0, 1);                                                             \
    if (t2 < nt) STG2(t2, 0, 2, 3);                                           \
    __builtin_amdgcn_s_barrier();                                             \
    LWAIT; MFMA16(1);                                                         \
    __builtin_amdgcn_s_barrier();                                             \
    RDB(1, 1); RDA(1, 1, 0);                                                  \
    __builtin_amdgcn_s_barrier();                                             \
    LWAIT; MFMA16(0);                                                         \
    __builtin_amdgcn_s_barrier();                                             \
    RDA(1, 1, 1);                                                             \
    __builtin_amdgcn_s_barrier();                                             \
    LWAIT; MFMA16(1);                                                         \
    VDRAIN;                                                                   \
    __builtin_amdgcn_s_barrier();                                             \
  }

// ======== FF1: hardcoded 8-phase 256x256 BK=64 (R9-proven: <78us) ========
__global__ __launch_bounds__(512, 1) void gemm8pf1(const unsigned short* __restrict__ A,
                                                   const unsigned short* __restrict__ Bt,
                                                   const float* __restrict__ bias,
                                                   unsigned short* __restrict__ C) {
  const int N = 4096, K = 1024;
  __shared__ unsigned short Ls[2][2][256 * 64];
  const int tid = threadIdx.x;
  const int w = tid >> 6;
  const int lane = tid & 63;

  const int id = blockIdx.x;                 // 512 blocks, %8==0 -> bijective swizzle
  const int lid = (id & 7) * 64 + (id >> 3);
  const int bm = (lid >> 4) * 256;
  const int bn = (lid & 15) * 256;

  const int wm = (w & 1) * 128, wn = (w >> 1) * 64;

  f32x4 acc[8][4];
#pragma unroll
  for (int i = 0; i < 8; ++i)
#pragma unroll
    for (int j = 0; j < 4; ++j) acc[i][j] = (f32x4){0.f, 0.f, 0.f, 0.f};

  const int srow = lane >> 3;
  const int skb = (lane & 7) ^ srow;
  const unsigned short* Ap[4];
  const unsigned short* Bp[4];
#pragma unroll
  for (int p = 0; p < 4; ++p) {
    const int u = w * 4 + p;
    Ap[p] = A + (size_t)(bm + u * 8 + srow) * K + skb * 8;
    Bp[p] = Bt + (size_t)(bn + u * 8 + srow) * K + skb * 8;
  }

  const int fr = lane & 15;
  const int g = lane >> 4;
  const int sw = fr & 7;

  bf16x8 av[4], bv[4];

  const int nt = 16;  // K/64
  STG2(0, 0, 0, 1);
  STG2(0, 0, 2, 3);
  VDRAIN;
  __builtin_amdgcn_s_barrier();

  for (int i = 0; i < 8; ++i) {
    const int t1 = 2 * i + 1;
    const int t2 = 2 * i + 2;
    EIGHT_PHASE_ITER(t1, t2, nt);
  }

  // bias + relu + bf16 store
#pragma unroll
  for (int im = 0; im < 8; ++im) {
    const int row0 = bm + wm + im * 16 + g * 4;
#pragma unroll
    for (int in = 0; in < 4; ++in) {
      const int col = bn + wn + in * 16 + fr;
      const float bvv = bias[col];
#pragma unroll
      for (int r = 0; r < 4; ++r) {
        float v = acc[im][in][r] + bvv;
        v = fmaxf(v, 0.0f);
        C[(size_t)(row0 + r) * N + col] = f2bf(v);
      }
    }
  }
}

// ======== QKV: hardcoded 8-phase 256x256, fused RoPE (Q,K) + transposed V store ========
// M=8192, N=3072, K=1024, grid 384 (%8==0). Wave owns 128x64 -> cbase is 64-aligned,
// typ/hh segment logic identical to the R1-proven 128x128 epilogue. Row mapping
// bm+wm+im*16+g*4+r identical (verified C/D layout). K-accum order unchanged.
__global__ __launch_bounds__(512, 1) void gemm8pqkv(const unsigned short* __restrict__ A,
                                                    const unsigned short* __restrict__ Bt,
                                                    const float* __restrict__ bias,
                                                    unsigned short* __restrict__ QKV,
                                                    unsigned short* __restrict__ Vt) {
  const int K = 1024;
  __shared__ unsigned short Ls[2][2][256 * 64];
  const int tid = threadIdx.x;
  const int w = tid >> 6;
  const int lane = tid & 63;

  const int id = blockIdx.x;                 // 384 blocks
  const int lid = (id & 7) * 48 + (id >> 3);
  const int bm = (lid / 12) * 256;           // 32 M-tiles
  const int bn = (lid % 12) * 256;           // 12 N-tiles

  const int wm = (w & 1) * 128, wn = (w >> 1) * 64;

  f32x4 acc[8][4];
#pragma unroll
  for (int i = 0; i < 8; ++i)
#pragma unroll
    for (int j = 0; j < 4; ++j) acc[i][j] = (f32x4){0.f, 0.f, 0.f, 0.f};

  const int srow = lane >> 3;
  const int skb = (lane & 7) ^ srow;
  const unsigned short* Ap[4];
  const unsigned short* Bp[4];
#pragma unroll
  for (int p = 0; p < 4; ++p) {
    const int u = w * 4 + p;
    Ap[p] = A + (size_t)(bm + u * 8 + srow) * K + skb * 8;
    Bp[p] = Bt + (size_t)(bn + u * 8 + srow) * K + skb * 8;
  }

  const int fr = lane & 15;
  const int g = lane >> 4;
  const int sw = fr & 7;

  bf16x8 av[4], bv[4];

  const int nt = 16;  // K/64
  STG2(0, 0, 0, 1);
  STG2(0, 0, 2, 3);
  VDRAIN;
  __builtin_amdgcn_s_barrier();

  for (int i = 0; i < 8; ++i) {
    const int t1 = 2 * i + 1;
    const int t2 = 2 * i + 2;
    EIGHT_PHASE_ITER(t1, t2, nt);
  }

  const int cbase = bn + wn;
  const int seg = cbase >> 6;
  const int typ = seg >> 4;   // 0=Q, 1=K, 2=V
  const int hh = seg & 15;
  const int bidx = bm >> 10;
  float bb[4];
#pragma unroll
  for (int in = 0; in < 4; ++in) bb[in] = bias[cbase + in * 16 + fr];

  if (typ == 2) {
#pragma unroll
    for (int im = 0; im < 8; ++im) {
      const int s0 = (bm & 1023) + wm + im * 16 + g * 4;
#pragma unroll
      for (int in = 0; in < 4; ++in) {
        const int d = in * 16 + fr;
        ushort4 o4;
        o4.x = f2bf(acc[im][in][0] + bb[in]);
        o4.y = f2bf(acc[im][in][1] + bb[in]);
        o4.z = f2bf(acc[im][in][2] + bb[in]);
        o4.w = f2bf(acc[im][in][3] + bb[in]);
        *(ushort4*)&Vt[(size_t)((bidx * 16 + hh) * 64 + d) * S_ + s0] = o4;
      }
    }
  } else {
    const float qs = (typ == 0) ? QSCALE : 1.0f;
    const float i0 = exp2f(-LG2_10K * (float)fr);
    const float i1 = exp2f(-LG2_10K * (float)(fr + 16));
#pragma unroll
    for (int im = 0; im < 8; ++im) {
      const int row0 = bm + wm + im * 16 + g * 4;
#pragma unroll
      for (int r = 0; r < 4; ++r) {
        const int row = row0 + r;
        const float s = (float)(row & 1023);
        float sn0, cs0, sn1, cs1;
        __sincosf(s * i0, &sn0, &cs0);
        __sincosf(s * i1, &sn1, &cs1);
        const float x0 = acc[im][0][r] + bb[0];
        const float x1 = acc[im][1][r] + bb[1];
        const float x2 = acc[im][2][r] + bb[2];
        const float x3 = acc[im][3][r] + bb[3];
        unsigned short* cp = QKV + (size_t)row * 3072 + cbase;
        cp[fr]      = f2bf((x0 * cs0 - x2 * sn0) * qs);
        cp[16 + fr] = f2bf((x1 * cs1 - x3 * sn1) * qs);
        cp[32 + fr] = f2bf((x2 * cs0 + x0 * sn0) * qs);
        cp[48 + fr] = f2bf((x3 * cs1 + x1 * sn1) * qs);
      }
    }
  }
}

// ======== FF2: hardcoded 8-phase split-K=2 (R6-proven ~52us) ========
__global__ __launch_bounds__(512, 1) void gemm256p(const unsigned short* __restrict__ A,
                                                   const unsigned short* __restrict__ Bt,
                                                   unsigned short* __restrict__ Pp) {
  const int M = 8192, N = 1024, K = 4096, KH = 2048;
  __shared__ unsigned short Ls[2][2][256 * 64];
  const int tid = threadIdx.x;
  const int w = tid >> 6;
  const int lane = tid & 63;

  int id = blockIdx.x;
  const int kh = id >> 7;
  id &= 127;
  const int lid = (id & 7) * 16 + (id >> 3);
  const int bm = (lid >> 2) * 256;
  const int bn = (lid & 3) * 256;

  const unsigned short* Ab = A + (size_t)kh * KH;
  const unsigned short* Bb = Bt + (size_t)kh * KH;

  const int wm = (w & 1) * 128, wn = (w >> 1) * 64;

  f32x4 acc[8][4];
#pragma unroll
  for (int i = 0; i < 8; ++i)
#pragma unroll
    for (int j = 0; j < 4; ++j) acc[i][j] = (f32x4){0.f, 0.f, 0.f, 0.f};

  const int srow = lane >> 3;
  const int skb = (lane & 7) ^ srow;
  const unsigned short* Ap[4];
  const unsigned short* Bp[4];
#pragma unroll
  for (int p = 0; p < 4; ++p) {
    const int u = w * 4 + p;
    Ap[p] = Ab + (size_t)(bm + u * 8 + srow) * K + skb * 8;
    Bp[p] = Bb + (size_t)(bn + u * 8 + srow) * K + skb * 8;
  }

  const int fr = lane & 15;
  const int g = lane >> 4;
  const int sw = fr & 7;

  bf16x8 av[4], bv[4];

  const int nt = 32;  // KH/64
  STG2(0, 0, 0, 1);
  STG2(0, 0, 2, 3);
  VDRAIN;
  __builtin_amdgcn_s_barrier();

  for (int i = 0; i < 16; ++i) {
    const int t1 = 2 * i + 1;
    const int t2 = 2 * i + 2;
    EIGHT_PHASE_ITER(t1, t2, nt);
  }

  unsigned short* P = Pp + (size_t)kh * ((size_t)M * N);
#pragma unroll
  for (int im = 0; im < 8; ++im) {
    const int row0 = bm + wm + im * 16 + g * 4;
#pragma unroll
    for (int in = 0; in < 4; ++in) {
      const int col = bn + wn + in * 16 + fr;
#pragma unroll
      for (int r = 0; r < 4; ++r)
        P[(size_t)(row0 + r) * N + col] = f2bf(acc[im][in][r]);
    }
  }
}

// ---------------- FF2 combine: out = x1 + b2 + P0 + P1 ----------------
__global__ __launch_bounds__(256) void ff2_reduce(const unsigned short* __restrict__ Pp,
                                                  const float* __restrict__ x1,
                                                  const float* __restrict__ b2,
                                                  float* __restrict__ out) {
  const int i = blockIdx.x * 256 + threadIdx.x;
  const size_t off = (size_t)i * 4;
  const ushort4 p0 = *(const ushort4*)(Pp + off);
  const ushort4 p1 = *(const ushort4*)(Pp + (8u << 20) + off);
  const float4 xv = *(const float4*)(x1 + off);
  const float4 bv = *(const float4*)(b2 + (off & 1023));
  float4 o;
  o.x = xv.x + bv.x + bf2f(p0.x) + bf2f(p1.x);
  o.y = xv.y + bv.y + bf2f(p0.y) + bf2f(p1.y);
  o.z = xv.z + bv.z + bf2f(p0.z) + bf2f(p1.z);
  o.w = xv.w + bv.w + bf2f(p0.w) + bf2f(p1.w);
  *(float4*)(out + off) = o;
}

// ---------------- bf16 MFMA GEMM 128x128, BK=64, XCD-swizzled 1D grid ------------
// R1-proven ~800 TF. Used for O-proj (res=x, fp32 out).
template <int OUT_BF16, int RELU, int RES>
__global__ __launch_bounds__(256) void gemm_bf16(const unsigned short* __restrict__ A,
                                                 const unsigned short* __restrict__ Bt,
                                                 const float* __restrict__ bias,
                                                 const float* __restrict__ res,
                                                 void* __restrict__ C,
                                                 int M, int N, int K) {
  __shared__ unsigned short As[128 * 64];
  __shared__ unsigned short Bs[128 * 64];
  const int tid = threadIdx.x;
  const int w = tid >> 6;
  const int lane = tid & 63;

  const int nb = gridDim.x;
  const int id = blockIdx.x;
  const int lid = (id & 7) * (nb >> 3) + (id >> 3);
  const int per = (M >> 7) * 8;
  const int grp = lid / per;
  const int rem = lid - grp * per;
  const int bn = (grp * 8 + (rem & 7)) * 128;
  const int bm = (rem >> 3) * 128;

  const int wm = (w & 1) * 64, wn = (w >> 1) * 64;

  f32x4 acc[4][4];
#pragma unroll
  for (int i = 0; i < 4; ++i)
#pragma unroll
    for (int j = 0; j < 4; ++j) acc[i][j] = (f32x4){0.f, 0.f, 0.f, 0.f};

  const int srow = lane >> 3;
  const int skb = (lane & 7) ^ srow;  // swizzled source 16B-slot
  const unsigned short* Ap[4];
  const unsigned short* Bp[4];
  unsigned short* AsD[4];
  unsigned short* BsD[4];
#pragma unroll
  for (int p = 0; p < 4; ++p) {
    const int u = w * 4 + p;
    Ap[p] = A + (size_t)(bm + u * 8 + srow) * K + skb * 8;
    Bp[p] = Bt + (size_t)(bn + u * 8 + srow) * K + skb * 8;
    AsD[p] = &As[u * 512 + lane * 8];
    BsD[p] = &Bs[u * 512 + lane * 8];
  }

  const int fr = lane & 15;
  const int g = lane >> 4;
  const int sw = fr & 7;

  for (int k0 = 0; k0 < K; k0 += 64) {
    __syncthreads();
#pragma unroll
    for (int p = 0; p < 4; ++p) glds16(Ap[p] + k0, AsD[p]);
#pragma unroll
    for (int p = 0; p < 4; ++p) glds16(Bp[p] + k0, BsD[p]);
    __syncthreads();
    bf16x8 a[4][2], b[4][2];
#pragma unroll
    for (int im = 0; im < 4; ++im)
#pragma unroll
      for (int kc = 0; kc < 2; ++kc)
        a[im][kc] = *(const bf16x8*)&As[(wm + im * 16 + fr) * 64 + ((kc * 4 + g) ^ sw) * 8];
#pragma unroll
    for (int in = 0; in < 4; ++in)
#pragma unroll
      for (int kc = 0; kc < 2; ++kc)
        b[in][kc] = *(const bf16x8*)&Bs[(wn + in * 16 + fr) * 64 + ((kc * 4 + g) ^ sw) * 8];
#pragma unroll
    for (int im = 0; im < 4; ++im)
#pragma unroll
      for (int in = 0; in < 4; ++in) {
        acc[im][in] = __builtin_amdgcn_mfma_f32_16x16x32_bf16(a[im][0], b[in][0], acc[im][in], 0, 0, 0);
        acc[im][in] = __builtin_amdgcn_mfma_f32_16x16x32_bf16(a[im][1], b[in][1], acc[im][in], 0, 0, 0);
      }
  }

#pragma unroll
  for (int im = 0; im < 4; ++im) {
    const int row0 = bm + wm + im * 16 + (lane >> 4) * 4;
#pragma unroll
    for (int in = 0; in < 4; ++in) {
      const int col = bn + wn + in * 16 + fr;
      const float bv = bias[col];
#pragma unroll
      for (int r = 0; r < 4; ++r) {
        float v = acc[im][in][r] + bv;
        if (RES) v += res[(size_t)(row0 + r) * N + col];
        if (RELU) v = fmaxf(v, 0.0f);
        if (OUT_BF16)
          ((unsigned short*)C)[(size_t)(row0 + r) * N + col] = f2bf(v);
        else
          ((float*)C)[(size_t)(row0 + r) * N + col] = v;
      }
    }
  }
}

// ---------------- MFMA flash attention v4: S^T form + double-buffered K/V staging -------
__global__ __launch_bounds__(256) void attn_v4(const unsigned short* __restrict__ QKV,
                                               const unsigned short* __restrict__ Vt,
                                               unsigned short* __restrict__ Og) {
  __shared__ unsigned short Kf[2][8 * 512];
  __shared__ unsigned short Vf[2][8 * 512];
  __shared__ unsigned short Ps[4][32 * 72];
  const int tid = threadIdx.x;
  const int w = tid >> 6, lane = tid & 63;
  const int qt = blockIdx.x, bh = blockIdx.y;
  const int b = bh >> 4, h = bh & 15;
  const int fr = lane & 15, g = lane >> 4, fk = g * 8;
  const int q0w = qt * 128 + w * 32;

  bf16x8 qB[2][2];
#pragma unroll
  for (int nt = 0; nt < 2; ++nt)
#pragma unroll
    for (int c = 0; c < 2; ++c)
      qB[nt][c] = *(const bf16x8*)&QKV[(size_t)(b * S_ + q0w + nt * 16 + fr) * 3072 +
                                       h * 64 + c * 32 + fk];

  f32x4 o[4][2];
#pragma unroll
  for (int mt = 0; mt < 4; ++mt)
#pragma unroll
    for (int nt = 0; nt < 2; ++nt) o[mt][nt] = (f32x4){0.f, 0.f, 0.f, 0.f};
  float l[2] = {0.0f, 0.0f};

#define STAGE(kt, bufi)                                                                   \
  {                                                                                       \
    _Pragma("unroll") for (int p = 0; p < 4; ++p) {                                       \
      const int u = w * 4 + p;                                                            \
      if (u < 8) {                                                                        \
        const int mt = u >> 1, c = u & 1;                                                 \
        glds16(QKV + (size_t)(b * S_ + (kt) * 64 + mt * 16 + fr) * 3072 + 1024 + h * 64 + \
                   c * 32 + fk,                                                           \
               &Kf[bufi][u * 512]);                                                       \
      } else {                                                                            \
        const int v2 = u - 8, mt = v2 >> 1, c = v2 & 1;                                   \
        glds16(Vt + (size_t)(bh * 64 + mt * 16 + fr) * S_ + (kt) * 64 + c * 32 + fk,      \
               &Vf[bufi][v2 * 512]);                                                      \
      }                                                                                   \
    }                                                                                     \
  }

  STAGE(0, 0);

  for (int kt = 0; kt < 16; ++kt) {
    __syncthreads();
    if (kt < 15) STAGE(kt + 1, (kt + 1) & 1);
    const unsigned short* Kc = Kf[kt & 1];
    const unsigned short* Vc = Vf[kt & 1];

    f32x4 s[4][2];
#pragma unroll
    for (int mt = 0; mt < 4; ++mt) {
      const bf16x8 k0 = *(const bf16x8*)&Kc[(mt * 2 + 0) * 512 + lane * 8];
      const bf16x8 k1 = *(const bf16x8*)&Kc[(mt * 2 + 1) * 512 + lane * 8];
#pragma unroll
      for (int nt = 0; nt < 2; ++nt) {
        f32x4 a = (f32x4){0.f, 0.f, 0.f, 0.f};
        a = __builtin_amdgcn_mfma_f32_16x16x32_bf16(k0, qB[nt][0], a, 0, 0, 0);
        a = __builtin_amdgcn_mfma_f32_16x16x32_bf16(k1, qB[nt][1], a, 0, 0, 0);
        s[mt][nt] = a;
      }
    }

#pragma unroll
    for (int nt = 0; nt < 2; ++nt) {
      float rs = 0.0f;
#pragma unroll
      for (int mt = 0; mt < 4; ++mt)
#pragma unroll
        for (int r = 0; r < 4; ++r) {
          const float p = exp2f(s[mt][nt][r]);
          s[mt][nt][r] = p;
          rs += p;
        }
      rs += __shfl_xor(rs, 16);
      rs += __shfl_xor(rs, 32);
      l[nt] += rs;
    }

#pragma unroll
    for (int nt = 0; nt < 2; ++nt)
#pragma unroll
      for (int mt = 0; mt < 4; ++mt) {
        uint2 pk;
        pk.x = __builtin_amdgcn_perm(fbits(s[mt][nt][1]), fbits(s[mt][nt][0]), 0x07060302u);
        pk.y = __builtin_amdgcn_perm(fbits(s[mt][nt][3]), fbits(s[mt][nt][2]), 0x07060302u);
        *(uint2*)&Ps[w][(nt * 16 + fr) * 72 + mt * 16 + g * 4] = pk;
      }

    bf16x8 pB[2][2];
#pragma unroll
    for (int nt = 0; nt < 2; ++nt)
#pragma unroll
      for (int c = 0; c < 2; ++c)
        pB[nt][c] = *(const bf16x8*)&Ps[w][(nt * 16 + fr) * 72 + c * 32 + fk];
#pragma unroll
    for (int mt = 0; mt < 4; ++mt) {
      const bf16x8 v0 = *(const bf16x8*)&Vc[(mt * 2 + 0) * 512 + lane * 8];
      const bf16x8 v1 = *(const bf16x8*)&Vc[(mt * 2 + 1) * 512 + lane * 8];
#pragma unroll
      for (int nt = 0; nt < 2; ++nt) {
        o[mt][nt] = __builtin_amdgcn_mfma_f32_16x16x32_bf16(v0, pB[nt][0], o[mt][nt], 0, 0, 0);
        o[mt][nt] = __builtin_amdgcn_mfma_f32_16x16x32_bf16(v1, pB[nt][1], o[mt][nt], 0, 0, 0);
      }
    }
  }

  const float linv0 = 1.0f / l[0], linv1 = 1.0f / l[1];
#pragma unroll
  for (int nt = 0; nt < 2; ++nt) {
    const float li = nt ? linv1 : linv0;
#pragma unroll
    for (int mt = 0; mt < 4; ++mt) {
      uint2 pk;
      pk.x = __builtin_amdgcn_perm(fbits(o[mt][nt][1] * li), fbits(o[mt][nt][0] * li), 0x07060302u);
      pk.y = __builtin_amdgcn_perm(fbits(o[mt][nt][3] * li), fbits(o[mt][nt][2] * li), 0x07060302u);
      *(uint2*)&Ps[w][(nt * 16 + fr) * 72 + mt * 16 + g * 4] = pk;
    }
  }
  const int qr = lane >> 1, hf = lane & 1;
#pragma unroll
  for (int c = 0; c < 2; ++c) {
    const bf16x8 vv = *(const bf16x8*)&Ps[w][qr * 72 + hf * 16 + c * 32];
    *(bf16x8*)&Og[(size_t)(b * S_ + q0w + qr) * E_ + h * 64 + hf * 16 + c * 32] = vv;
  }
}

extern "C" void kernel_launch(void* const* d_in, const int* in_sizes, int n_in,
                              void* d_out, int out_size, void* d_ws, size_t ws_size,
                              hipStream_t stream) {
  const float* x  = (const float*)d_in[0];
  const float* WQ = (const float*)d_in[1];
  const float* bQ = (const float*)d_in[2];
  const float* WK = (const float*)d_in[3];
  const float* bK = (const float*)d_in[4];
  const float* WV = (const float*)d_in[5];
  const float* bV = (const float*)d_in[6];
  const float* WO = (const float*)d_in[7];
  const float* bO = (const float*)d_in[8];
  const float* W1 = (const float*)d_in[9];
  const float* b1 = (const float*)d_in[10];
  const float* W2 = (const float*)d_in[11];
  const float* b2 = (const float*)d_in[12];
  const float* g1 = (const float*)d_in[13];
  const float* g2 = (const float*)d_in[14];
  float* out = (float*)d_out;

  char* ws = (char*)d_ws;
  const size_t MB = 1024 * 1024;
  unsigned short* h1   = (unsigned short*)(ws + 0 * MB);
  unsigned short* QKV  = (unsigned short*)(ws + 16 * MB);   // [8192,3072]
  unsigned short* Vt   = (unsigned short*)(ws + 64 * MB);   // [128*64,1024]
  unsigned short* Ob   = (unsigned short*)(ws + 80 * MB);
  float*          x1   = (float*)(ws + 96 * MB);
  unsigned short* h2   = (unsigned short*)(ws + 128 * MB);
  unsigned short* mid  = (unsigned short*)(ws + 16 * MB);   // reuses QKV+Vt region
  unsigned short* WQKVt= (unsigned short*)(ws + 144 * MB);
  unsigned short* WOt  = (unsigned short*)(ws + 150 * MB);
  unsigned short* W1t  = (unsigned short*)(ws + 152 * MB);
  unsigned short* W2t  = (unsigned short*)(ws + 160 * MB);
  float*          bqkv = (float*)(ws + 168 * MB);
  unsigned short* Pp   = (unsigned short*)(ws + 176 * MB);  // [2][8192,1024] bf16 partials

  const int M = B_ * S_;

  prep<<<12300, 256, 0, stream>>>(WQ, WK, WV, WO, W1, W2, bQ, bK, bV,
                                  WQKVt, WOt, W1t, W2t, bqkv);

  rmsnorm_kernel<<<M, 256, 0, stream>>>(x, g1, h1);

  // QKV: hardcoded 8-phase 256x256 (replaces 128x128 gemm_qkv @78us)
  gemm8pqkv<<<384, 512, 0, stream>>>(h1, WQKVt, bqkv, QKV, Vt);

  attn_v4<<<dim3(8, B_ * H_), 256, 0, stream>>>(QKV, Vt, Ob);

  // O-proj: 128x128 tile, res-add x, fp32 out
  gemm_bf16<0, 0, 1><<<64 * 8, 256, 0, stream>>>(Ob, WOt, bO, x, x1, M, E_, E_);

  rmsnorm_kernel<<<M, 256, 0, stream>>>(x1, g2, h2);

  // FF1: hardcoded 8-phase (R9-proven < 78us)
  gemm8pf1<<<512, 512, 0, stream>>>(h2, W1t, b1, mid);

  // FF2: hardcoded 8-phase split-K=2 (R6-proven ~52us)
  gemm256p<<<256, 512, 0, stream>>>(mid, W2t, Pp);

  ff2_reduce<<<8192, 256, 0, stream>>>(Pp, x1, b2, out);
}